// Round 1
// 335.900 us; speedup vs baseline: 1.0894x; 1.0894x over previous
//
#include <hip/hip_runtime.h>
#include <hip/hip_bf16.h>
#include <math.h>

#define B_  4
#define C_  64
#define H_  128
#define W_  128
#define HS  64
#define WS  64
#define L_  4096
#define K1  576
#define E2  1024
#define KSPLIT 4
// f16 subnormal floor is 2^-24 (logit -16.635); values below 2^-25 (-17.33) cast
// to exactly 0. Flag threshold -17.5 is conservative: no nonzero f16 is missed.
#define ZLOG (-17.5f)

typedef _Float16 f16;
typedef f16 f16x8 __attribute__((ext_vector_type(8)));
typedef float f32x4 __attribute__((ext_vector_type(4)));

__device__ __forceinline__ void gload16(const void* g, void* l) {
    __builtin_amdgcn_global_load_lds(
        (const __attribute__((address_space(1))) unsigned int*)g,
        (__attribute__((address_space(3))) unsigned int*)l, 16, 0, 0);
}

// ---------------- bilinear resize 128->64, align_corners ----------------
__global__ __launch_bounds__(256) void resize_kernel(const float* __restrict__ fg,
                                                     float* __restrict__ fgs) {
    int idx = blockIdx.x * 256 + threadIdx.x;
    if (idx >= B_ * C_ * HS * WS) return;
    int j = idx & 63, i = (idx >> 6) & 63, bc = idx >> 12;
    const float sc = 127.0f / 63.0f;
    float yf = i * sc, xf = j * sc;
    int y0 = (int)floorf(yf); if (y0 > 127) y0 = 127;
    int x0 = (int)floorf(xf); if (x0 > 127) x0 = 127;
    int y1 = min(y0 + 1, 127), x1 = min(x0 + 1, 127);
    float wy = yf - (float)y0, wx = xf - (float)x0;
    const float* p = fg + (size_t)bc * (H_ * W_);
    float a = p[y0 * W_ + x0], b = p[y0 * W_ + x1];
    float c = p[y1 * W_ + x0], d = p[y1 * W_ + x1];
    float t0 = a * (1.f - wy) + c * wy;
    float t1 = b * (1.f - wy) + d * wy;
    fgs[idx] = t0 * (1.f - wx) + t1 * wx;
}

// ---------------- P[l,k] f16 patches (3x3xC, zero pad 1), batched ----------------
__global__ __launch_bounds__(256) void patch_kernel(const float* __restrict__ fgs,
                                                    f16* __restrict__ P_all) {
    int idx = blockIdx.x * 256 + threadIdx.x;
    int b = blockIdx.y;
    int k = idx % K1, l = idx / K1;
    int c = k / 9, r = k % 9;
    int dy = r / 3, dx = r % 3;
    int ly = l >> 6, lx = l & 63;
    int y = ly - 1 + dy, x = lx - 1 + dx;
    float v = 0.f;
    if ((unsigned)y < 64u && (unsigned)x < 64u)
        v = fgs[((size_t)b * C_ + c) * (HS * WS) + y * WS + x];
    P_all[(size_t)b * L_ * K1 + idx] = (f16)v;
}

// ---------------- norms of f16 patch rows (fp32 accumulate), batched ----------------
__global__ __launch_bounds__(64) void norm_kernel(const f16* __restrict__ P_all,
                                                  float* __restrict__ nrm_all) {
    int l = blockIdx.x, b = blockIdx.y, t = threadIdx.x;
    const f16* row = P_all + ((size_t)b * L_ + l) * K1;
    float s = 0.f;
    for (int k = t; k < K1; k += 64) { float v = (float)row[k]; s = fmaf(v, v, s); }
    #pragma unroll
    for (int off = 32; off; off >>= 1) s += __shfl_down(s, off);
    if (t == 0) nrm_all[b * L_ + l] = fmaxf(sqrtf(s), 1e-4f);
}

// ---------------- VT[e,l] f16 : transposed 4x4xC background patches, batched over grid.y ----------------
__global__ __launch_bounds__(256) void v_kernel(const float* __restrict__ bg_g,
                                                f16* __restrict__ VT_g) {
    int ls = blockIdx.y;
    const float* bg_b = bg_g + (size_t)ls * (C_ * H_ * W_);
    f16* VT = VT_g + (size_t)ls * ((size_t)E2 * L_);
    int idx = blockIdx.x * 256 + threadIdx.x;
    int l = idx & 4095, e = idx >> 12;
    int c = e >> 4, r = e & 15;
    int ky = r >> 2, kx = r & 3;
    int ly = l >> 6, lx = l & 63;
    int by = 2 * ly - 1 + ky, bx = 2 * lx - 1 + kx;
    float v = 0.f;
    if ((unsigned)by < 128u && (unsigned)bx < 128u)
        v = bg_b[(size_t)c * (H_ * W_) + by * W_ + bx];
    VT[idx] = (f16)v;
}

// ---------------- MFMA gemm_bt: D[M,N] = A[M,K] * Bt[N,K]^T, batched over grid.y ----------------
// 128x128 tile, 4 waves (2x2 of 64x64), 16x16x32 f16 MFMA, BK=64 (two BK-32
// panels, 32 MFMA per barrier pair, m97 staging).
// LDS chunk XOR-swizzle (T2 both-sides): staging source chunk = (lane&3)^((lane>>3)&3),
// fragment read chunk = quad^((mfm>>1)&3). Row stride stays 64B (gload_lds needs
// linear dest) but the 16B chunk permutation spreads the 16 mfm-lanes over 8
// bank-quadruples -> 2-way conflict (free) instead of 8-way.
// EPI=1 (score): E[p,l] = exp(acc*10/nrm[l] - 10*nrm[p]) stored f16, single exp
//   pass (acc overwritten in place, rowsum + store share the same values), only
//   for tiles whose max logit > ZLOG; per-tile nonzero flag written.
// EPI=0 (PV, split-K): skips whole BK-64 chunks whose E-tile flag is 0.
template <int EPI>
__global__ __launch_bounds__(256)
void mfma_gemm(const f16* __restrict__ A, size_t sA,
               const f16* __restrict__ Bt, size_t sB,
               int lda, int ldb, int kLen, void* __restrict__ outp, size_t sOut,
               int ldc, const float* __restrict__ nrm, float* __restrict__ rowsum,
               int* __restrict__ flags) {
    __shared__ __align__(16) f16 As0[128 * 32];
    __shared__ __align__(16) f16 As1[128 * 32];
    __shared__ __align__(16) f16 Bs0[128 * 32];
    __shared__ __align__(16) f16 Bs1[128 * 32];
    __shared__ float sred[4];

    const int ls = blockIdx.y;
    A  += (size_t)ls * sA;
    Bt += (size_t)ls * sB;
    f16* outbase = (f16*)outp + (size_t)ls * sOut;
    if (EPI == 1) { nrm += (size_t)ls * L_; rowsum += (size_t)ls * L_; }
    flags += ls * 1024;

    const int lin = blockIdx.x;
    int bx, by, bz;
    if (EPI == 1) { int xcd = lin & 7, i = lin >> 3; bx = i & 31; by = xcd + 8 * (i >> 5); bz = 0; }
    else          { by = lin & 7; int i = lin >> 3; bx = i & 31; bz = i >> 5; }

    const int tid = threadIdx.x;
    const int w = tid >> 6, lane = tid & 63;
    const int row0 = by * 128, col0 = bx * 128;
    const int k_start = bz * kLen;

    const int srow = w * 32 + (lane >> 2);
    // swizzled source chunk: LDS[row][q] holds global chunk q ^ ((row>>1)&3)
    const int scol = (((lane & 3) ^ ((lane >> 3) & 3)) * 8);
    const f16* gA = A + (size_t)(row0 + srow) * lda + k_start + scol;
    const f16* gB = Bt + (size_t)(col0 + srow) * ldb + k_start + scol;
    const int l0 = (w * 32) * 32, l1 = (w * 32 + 16) * 32;

    const int wm = w >> 1, wn = w & 1;
    const int mfm = lane & 15, quad = lane >> 4;
    // swizzled read chunk (element offset): undoes the staging permutation
    const int rq = (quad ^ ((mfm >> 1) & 3)) * 8;
    f32x4 acc[4][4] = {};

    for (int k0 = 0; k0 < kLen; k0 += 64) {
        if (EPI == 0) {
            // skip chunk if its 128x128 E-tile is all-zero (exact)
            if (!flags[(col0 >> 7) * 32 + ((k_start + k0) >> 7)]) continue;
        }
        gload16(gA + k0,                    As0 + l0);
        gload16(gA + k0 + (size_t)16 * lda, As0 + l1);
        gload16(gA + k0 + 32,               As1 + l0);
        gload16(gA + k0 + 32 + (size_t)16 * lda, As1 + l1);
        gload16(gB + k0,                    Bs0 + l0);
        gload16(gB + k0 + (size_t)16 * ldb, Bs0 + l1);
        gload16(gB + k0 + 32,               Bs1 + l0);
        gload16(gB + k0 + 32 + (size_t)16 * ldb, Bs1 + l1);
        __syncthreads();
        {
            f16x8 af[4], bf[4];
            #pragma unroll
            for (int mi = 0; mi < 4; ++mi)
                af[mi] = *(const f16x8*)&As0[(wm * 64 + mi * 16 + mfm) * 32 + rq];
            #pragma unroll
            for (int ni = 0; ni < 4; ++ni)
                bf[ni] = *(const f16x8*)&Bs0[(wn * 64 + ni * 16 + mfm) * 32 + rq];
            #pragma unroll
            for (int mi = 0; mi < 4; ++mi)
                #pragma unroll
                for (int ni = 0; ni < 4; ++ni)
                    acc[mi][ni] = __builtin_amdgcn_mfma_f32_16x16x32_f16(
                        af[mi], bf[ni], acc[mi][ni], 0, 0, 0);
        }
        {
            f16x8 af[4], bf[4];
            #pragma unroll
            for (int mi = 0; mi < 4; ++mi)
                af[mi] = *(const f16x8*)&As1[(wm * 64 + mi * 16 + mfm) * 32 + rq];
            #pragma unroll
            for (int ni = 0; ni < 4; ++ni)
                bf[ni] = *(const f16x8*)&Bs1[(wn * 64 + ni * 16 + mfm) * 32 + rq];
            #pragma unroll
            for (int mi = 0; mi < 4; ++mi)
                #pragma unroll
                for (int ni = 0; ni < 4; ++ni)
                    acc[mi][ni] = __builtin_amdgcn_mfma_f32_16x16x32_f16(
                        af[mi], bf[ni], acc[mi][ni], 0, 0, 0);
        }
        __syncthreads();
    }

    const int orow = row0 + wm * 64;
    const int ocol = col0 + wn * 64;
    if (EPI == 1) {
        f16* Eo = outbase;
        float rowm[16], cs[4];
        #pragma unroll
        for (int j = 0; j < 16; ++j)
            rowm[j] = 10.0f * nrm[orow + (j >> 2) * 16 + quad * 4 + (j & 3)];
        #pragma unroll
        for (int ni = 0; ni < 4; ++ni) cs[ni] = 10.0f / nrm[ocol + ni * 16 + mfm];
        // single pass: e computed once, acc overwritten in place
        float rs[16] = {};
        float mx = -1e30f;
        #pragma unroll
        for (int ni = 0; ni < 4; ++ni)
            #pragma unroll
            for (int mi = 0; mi < 4; ++mi)
                #pragma unroll
                for (int r = 0; r < 4; ++r) {
                    float lg = acc[mi][ni][r] * cs[ni] - rowm[mi * 4 + r];
                    mx = fmaxf(mx, lg);
                    float e = __expf(lg);
                    acc[mi][ni][r] = e;
                    rs[mi * 4 + r] += e;
                }
        #pragma unroll
        for (int off = 32; off; off >>= 1) mx = fmaxf(mx, __shfl_xor(mx, off));
        if (lane == 0) sred[w] = mx;
        __syncthreads();
        float bmax = fmaxf(fmaxf(sred[0], sred[1]), fmaxf(sred[2], sred[3]));
        int nz = bmax > ZLOG;
        if (nz) {
            #pragma unroll
            for (int ni = 0; ni < 4; ++ni) {
                int col = ocol + ni * 16 + mfm;
                #pragma unroll
                for (int mi = 0; mi < 4; ++mi)
                    #pragma unroll
                    for (int r = 0; r < 4; ++r) {
                        int row = orow + mi * 16 + quad * 4 + r;
                        Eo[(size_t)row * ldc + col] = (f16)acc[mi][ni][r];
                    }
            }
            #pragma unroll
            for (int j = 0; j < 16; ++j) {
                float v = rs[j];
                v += __shfl_xor(v, 1); v += __shfl_xor(v, 2);
                v += __shfl_xor(v, 4); v += __shfl_xor(v, 8);
                if (mfm == 0)
                    atomicAdd(&rowsum[orow + (j >> 2) * 16 + quad * 4 + (j & 3)], v);
            }
        }
        if (tid == 0) flags[by * 32 + bx] = nz;
    } else {
        f16* Oo = outbase + (size_t)bz * ((size_t)E2 * L_);
        #pragma unroll
        for (int mi = 0; mi < 4; ++mi) {
            #pragma unroll
            for (int r = 0; r < 4; ++r) {
                int row = orow + mi * 16 + quad * 4 + r;
                #pragma unroll
                for (int ni = 0; ni < 4; ++ni)
                    Oo[(size_t)row * ldc + ocol + ni * 16 + mfm] = (f16)acc[mi][ni][r];
            }
        }
    }
}

// ---------------- conv_transpose overlap-add gather on OPT[s][e][p] layout, batched ----------------
__global__ __launch_bounds__(256) void gather_kernel(const f16* __restrict__ OPT_g,
                                                     const float* __restrict__ rowsum_g,
                                                     float* __restrict__ out_g) {
    int ls = blockIdx.y;
    const f16* OPT = OPT_g + (size_t)ls * ((size_t)KSPLIT * E2 * L_);
    const float* rowsum = rowsum_g + (size_t)ls * L_;
    float* out_b = out_g + (size_t)ls * (C_ * H_ * W_);
    int idx = blockIdx.x * 256 + threadIdx.x;
    if (idx >= C_ * H_ * W_) return;
    int X = idx & 127, Y = (idx >> 7) & 127, c = idx >> 14;
    int kyp = (Y + 1) & 1;
    int kxp = (X + 1) & 1;
    float sum = 0.f;
    #pragma unroll
    for (int ky = kyp; ky < 4; ky += 2) {
        int py = (Y + 1 - ky) >> 1;
        if ((unsigned)py >= 64u) continue;
        #pragma unroll
        for (int kx = kxp; kx < 4; kx += 2) {
            int px = (X + 1 - kx) >> 1;
            if ((unsigned)px >= 64u) continue;
            int p = py * 64 + px;
            int e = c * 16 + ky * 4 + kx;
            float v = 0.f;
            #pragma unroll
            for (int s = 0; s < KSPLIT; ++s)
                v += (float)OPT[((size_t)s * E2 + e) * L_ + p];
            sum += v * __builtin_amdgcn_rcpf(rowsum[p]);
        }
    }
    out_b[idx] = 0.25f * sum;
}

extern "C" void kernel_launch(void* const* d_in, const int* in_sizes, int n_in,
                              void* d_out, int out_size, void* d_ws, size_t ws_size,
                              hipStream_t stream) {
    const float* bg = (const float*)d_in[0];
    const float* fg = (const float*)d_in[1];
    float* out = (float*)d_out;
    char* w8 = (char*)d_ws;

    // fixed workspace region (bytes)
    float* fgs        = (float*)(w8);                 //  4,194,304
    f16*   P_all      = (f16*)  (w8 + 4194304);       // 18,874,368
    float* nrm        = (float*)(w8 + 23068672);      //     65,536
    float* rowsum_all = (float*)(w8 + 23134208);      //     65,536 (B_ x L_)
    int*   flags      = (int*)  (w8 + 23199744);      //     16,384 (B_ x 32x32 tile flags)
    const size_t base = 23216128;

    // per-sample buffers: VT 8 MiB + Eb 32 MiB + OPT 32 MiB = 72 MiB.
    // batch as many samples per launch round as the workspace allows:
    // nb=4 -> 325.2 MB total, nb=2 -> 174.2 MB, nb=1 -> 98.7 MB (proven fits).
    const size_t perVT  = (size_t)E2 * L_ * 2;        //  8,388,608
    const size_t perEb  = (size_t)L_ * L_ * 2;        // 33,554,432
    const size_t perOPT = (size_t)KSPLIT * E2 * L_ * 2; // 33,554,432
    const size_t per = perVT + perEb + perOPT;
    int nb = 1;
    if (ws_size >= base + 4 * per) nb = 4;
    else if (ws_size >= base + 2 * per) nb = 2;

    f16* VT  = (f16*)(w8 + base);
    f16* Eb  = (f16*)(w8 + base + (size_t)nb * perVT);
    f16* OPT = (f16*)(w8 + base + (size_t)nb * (perVT + perEb));

    resize_kernel<<<(B_ * C_ * HS * WS) / 256, 256, 0, stream>>>(fg, fgs);
    patch_kernel<<<dim3((L_ * K1) / 256, B_), 256, 0, stream>>>(fgs, P_all);
    norm_kernel<<<dim3(L_, B_), 64, 0, stream>>>(P_all, nrm);
    hipMemsetAsync(rowsum_all, 0, (size_t)B_ * L_ * sizeof(float), stream);

    for (int g = 0; g < B_; g += nb) {
        const f16* P_g     = P_all + (size_t)g * L_ * K1;
        const float* nrm_g = nrm + (size_t)g * L_;
        float* rowsum_g    = rowsum_all + (size_t)g * L_;
        int* flags_g       = flags + g * 1024;

        v_kernel<<<dim3((L_ * E2) / 256, nb), 256, 0, stream>>>(
            bg + (size_t)g * C_ * H_ * W_, VT);

        // E[p,l] = exp(10*<P_p,P_l>/nrm[l] - 10*nrm[p]); rowsum[p] += E; tile flags
        mfma_gemm<1><<<dim3(1024, nb), 256, 0, stream>>>(
            P_g, (size_t)L_ * K1, P_g, (size_t)L_ * K1,
            K1, K1, K1, Eb, (size_t)L_ * L_, L_,
            nrm_g, rowsum_g, flags_g);

        // OPT_z[e,p] = sum_{l in slice z} VT[e,l] * E[p,l]  (skips zero E-tiles)
        mfma_gemm<0><<<dim3(1024, nb), 256, 0, stream>>>(
            VT, (size_t)E2 * L_, Eb, (size_t)L_ * L_,
            L_, L_, L_ / KSPLIT, OPT, (size_t)KSPLIT * E2 * L_, L_,
            nullptr, nullptr, flags_g);

        gather_kernel<<<dim3((C_ * H_ * W_) / 256, nb), 256, 0, stream>>>(
            OPT, rowsum_g, out + (size_t)g * C_ * H_ * W_);
    }
}

// Round 2
// 329.661 us; speedup vs baseline: 1.1101x; 1.0189x over previous
//
#include <hip/hip_runtime.h>
#include <hip/hip_bf16.h>
#include <math.h>

#define B_  4
#define C_  64
#define H_  128
#define W_  128
#define HS  64
#define WS  64
#define L_  4096
#define K1  576
#define E2  1024
#define KSPLIT 4
// f16 subnormal floor is 2^-24 (logit -16.635); values below 2^-25 (-17.33) cast
// to exactly 0. Flag threshold -17.5 is conservative: no nonzero f16 is missed.
#define ZLOG (-17.5f)

typedef _Float16 f16;
typedef f16 f16x8 __attribute__((ext_vector_type(8)));
typedef float f32x4 __attribute__((ext_vector_type(4)));

__device__ __forceinline__ void gload16(const void* g, void* l) {
    __builtin_amdgcn_global_load_lds(
        (const __attribute__((address_space(1))) unsigned int*)g,
        (__attribute__((address_space(3))) unsigned int*)l, 16, 0, 0);
}

// ---------------- bilinear resize 128->64, align_corners ----------------
__global__ __launch_bounds__(256) void resize_kernel(const float* __restrict__ fg,
                                                     float* __restrict__ fgs) {
    int idx = blockIdx.x * 256 + threadIdx.x;
    if (idx >= B_ * C_ * HS * WS) return;
    int j = idx & 63, i = (idx >> 6) & 63, bc = idx >> 12;
    const float sc = 127.0f / 63.0f;
    float yf = i * sc, xf = j * sc;
    int y0 = (int)floorf(yf); if (y0 > 127) y0 = 127;
    int x0 = (int)floorf(xf); if (x0 > 127) x0 = 127;
    int y1 = min(y0 + 1, 127), x1 = min(x0 + 1, 127);
    float wy = yf - (float)y0, wx = xf - (float)x0;
    const float* p = fg + (size_t)bc * (H_ * W_);
    float a = p[y0 * W_ + x0], b = p[y0 * W_ + x1];
    float c = p[y1 * W_ + x0], d = p[y1 * W_ + x1];
    float t0 = a * (1.f - wy) + c * wy;
    float t1 = b * (1.f - wy) + d * wy;
    fgs[idx] = t0 * (1.f - wx) + t1 * wx;
}

// ---------------- P[l,k] f16 patches (3x3xC, zero pad 1), batched ----------------
__global__ __launch_bounds__(256) void patch_kernel(const float* __restrict__ fgs,
                                                    f16* __restrict__ P_all) {
    int idx = blockIdx.x * 256 + threadIdx.x;
    int b = blockIdx.y;
    int k = idx % K1, l = idx / K1;
    int c = k / 9, r = k % 9;
    int dy = r / 3, dx = r % 3;
    int ly = l >> 6, lx = l & 63;
    int y = ly - 1 + dy, x = lx - 1 + dx;
    float v = 0.f;
    if ((unsigned)y < 64u && (unsigned)x < 64u)
        v = fgs[((size_t)b * C_ + c) * (HS * WS) + y * WS + x];
    P_all[(size_t)b * L_ * K1 + idx] = (f16)v;
}

// ---------------- norms of f16 patch rows (fp32 accumulate), batched ----------------
__global__ __launch_bounds__(64) void norm_kernel(const f16* __restrict__ P_all,
                                                  float* __restrict__ nrm_all) {
    int l = blockIdx.x, b = blockIdx.y, t = threadIdx.x;
    const f16* row = P_all + ((size_t)b * L_ + l) * K1;
    float s = 0.f;
    for (int k = t; k < K1; k += 64) { float v = (float)row[k]; s = fmaf(v, v, s); }
    #pragma unroll
    for (int off = 32; off; off >>= 1) s += __shfl_down(s, off);
    if (t == 0) nrm_all[b * L_ + l] = fmaxf(sqrtf(s), 1e-4f);
}

// ---------------- VT[e,l] f16 : transposed 4x4xC background patches, batched over grid.y ----------------
__global__ __launch_bounds__(256) void v_kernel(const float* __restrict__ bg_g,
                                                f16* __restrict__ VT_g) {
    int ls = blockIdx.y;
    const float* bg_b = bg_g + (size_t)ls * (C_ * H_ * W_);
    f16* VT = VT_g + (size_t)ls * ((size_t)E2 * L_);
    int idx = blockIdx.x * 256 + threadIdx.x;
    int l = idx & 4095, e = idx >> 12;
    int c = e >> 4, r = e & 15;
    int ky = r >> 2, kx = r & 3;
    int ly = l >> 6, lx = l & 63;
    int by = 2 * ly - 1 + ky, bx = 2 * lx - 1 + kx;
    float v = 0.f;
    if ((unsigned)by < 128u && (unsigned)bx < 128u)
        v = bg_b[(size_t)c * (H_ * W_) + by * W_ + bx];
    VT[idx] = (f16)v;
}

// ---------------- MFMA gemm_bt: D[M,N] = A[M,K] * Bt[N,K]^T, batched over grid.y ----------------
// 128x128 tile, 4 waves (2x2 of 64x64), 16x16x32 f16 MFMA, BK=64.
// T3 "minimum 2-phase" pipeline: double-buffered BK-64 chunks (64 KB LDS),
// prefetch of chunk t+1 issued BEFORE compute of chunk t, ONE __syncthreads
// per chunk (its vmcnt(0)+lgkmcnt(0) drain covers both the prefetch residual
// and the LDS write-after-read hazard; race-free by full-barrier semantics).
// Register file (~164 unified VGPR+AGPR) caps residency at 2 blocks/CU anyway,
// so the 64 KB LDS costs no occupancy.
// LDS chunk XOR-swizzle (T2 both-sides): staging source chunk = (lane&3)^((lane>>3)&3),
// fragment read chunk = quad^((mfm>>1)&3) -> 0 bank conflicts (verified r1).
// EPI=1 (score): E[p,l] = exp(acc*10/nrm[l] - 10*nrm[p]) stored f16, single exp
//   pass, only for tiles whose max logit > ZLOG; per-tile nonzero flag written.
// EPI=0 (PV, split-K): skips BK-64 chunks whose 128x128 E-tile flag is 0
//   (next-valid-chunk search feeding the prefetch; exact as before).
template <int EPI>
__global__ __launch_bounds__(256)
void mfma_gemm(const f16* __restrict__ A, size_t sA,
               const f16* __restrict__ Bt, size_t sB,
               int lda, int ldb, int kLen, void* __restrict__ outp, size_t sOut,
               int ldc, const float* __restrict__ nrm, float* __restrict__ rowsum,
               int* __restrict__ flags) {
    // [buf][half][128 rows x 32 cols]
    __shared__ __align__(16) f16 As[2][2][128 * 32];
    __shared__ __align__(16) f16 Bs[2][2][128 * 32];
    __shared__ float sred[4];

    const int ls = blockIdx.y;
    A  += (size_t)ls * sA;
    Bt += (size_t)ls * sB;
    f16* outbase = (f16*)outp + (size_t)ls * sOut;
    if (EPI == 1) { nrm += (size_t)ls * L_; rowsum += (size_t)ls * L_; }
    flags += ls * 1024;

    const int lin = blockIdx.x;
    int bx, by, bz;
    if (EPI == 1) { int xcd = lin & 7, i = lin >> 3; bx = i & 31; by = xcd + 8 * (i >> 5); bz = 0; }
    else          { by = lin & 7; int i = lin >> 3; bx = i & 31; bz = i >> 5; }

    const int tid = threadIdx.x;
    const int w = tid >> 6, lane = tid & 63;
    const int row0 = by * 128, col0 = bx * 128;
    const int k_start = bz * kLen;

    const int srow = w * 32 + (lane >> 2);
    // swizzled source chunk: LDS[row][q] holds global chunk q ^ ((row>>1)&3)
    const int scol = (((lane & 3) ^ ((lane >> 3) & 3)) * 8);
    const f16* gA = A + (size_t)(row0 + srow) * lda + k_start + scol;
    const f16* gB = Bt + (size_t)(col0 + srow) * ldb + k_start + scol;
    const int l0 = (w * 32) * 32, l1 = (w * 32 + 16) * 32;

    const int wm = w >> 1, wn = w & 1;
    const int mfm = lane & 15, quad = lane >> 4;
    // swizzled read chunk (element offset): undoes the staging permutation
    const int rq = (quad ^ ((mfm >> 1) & 3)) * 8;
    f32x4 acc[4][4] = {};

    int kc = 0;
    if (EPI == 0) {
        while (kc < kLen && !flags[(col0 >> 7) * 32 + ((k_start + kc) >> 7)]) kc += 64;
    }
    if (kc < kLen) {
        int cur = 0;
        // prologue: stage chunk kc into buffer 0
        gload16(gA + kc,                         &As[0][0][l0]);
        gload16(gA + kc + (size_t)16 * lda,      &As[0][0][l1]);
        gload16(gA + kc + 32,                    &As[0][1][l0]);
        gload16(gA + kc + 32 + (size_t)16 * lda, &As[0][1][l1]);
        gload16(gB + kc,                         &Bs[0][0][l0]);
        gload16(gB + kc + (size_t)16 * ldb,      &Bs[0][0][l1]);
        gload16(gB + kc + 32,                    &Bs[0][1][l0]);
        gload16(gB + kc + 32 + (size_t)16 * ldb, &Bs[0][1][l1]);
        __syncthreads();
        for (;;) {
            int kn = kc + 64;
            if (EPI == 0) {
                while (kn < kLen && !flags[(col0 >> 7) * 32 + ((k_start + kn) >> 7)]) kn += 64;
            }
            if (kn < kLen) {
                const int nxt = cur ^ 1;
                gload16(gA + kn,                         &As[nxt][0][l0]);
                gload16(gA + kn + (size_t)16 * lda,      &As[nxt][0][l1]);
                gload16(gA + kn + 32,                    &As[nxt][1][l0]);
                gload16(gA + kn + 32 + (size_t)16 * lda, &As[nxt][1][l1]);
                gload16(gB + kn,                         &Bs[nxt][0][l0]);
                gload16(gB + kn + (size_t)16 * ldb,      &Bs[nxt][0][l1]);
                gload16(gB + kn + 32,                    &Bs[nxt][1][l0]);
                gload16(gB + kn + 32 + (size_t)16 * ldb, &Bs[nxt][1][l1]);
            }
            #pragma unroll
            for (int h = 0; h < 2; ++h) {
                f16x8 af[4], bf[4];
                #pragma unroll
                for (int mi = 0; mi < 4; ++mi)
                    af[mi] = *(const f16x8*)&As[cur][h][(wm * 64 + mi * 16 + mfm) * 32 + rq];
                #pragma unroll
                for (int ni = 0; ni < 4; ++ni)
                    bf[ni] = *(const f16x8*)&Bs[cur][h][(wn * 64 + ni * 16 + mfm) * 32 + rq];
                __builtin_amdgcn_s_setprio(1);
                #pragma unroll
                for (int mi = 0; mi < 4; ++mi)
                    #pragma unroll
                    for (int ni = 0; ni < 4; ++ni)
                        acc[mi][ni] = __builtin_amdgcn_mfma_f32_16x16x32_f16(
                            af[mi], bf[ni], acc[mi][ni], 0, 0, 0);
                __builtin_amdgcn_s_setprio(0);
            }
            __syncthreads();
            cur ^= 1;
            kc = kn;
            if (kc >= kLen) break;
        }
    }

    const int orow = row0 + wm * 64;
    const int ocol = col0 + wn * 64;
    if (EPI == 1) {
        f16* Eo = outbase;
        float rowm[16], cs[4];
        #pragma unroll
        for (int j = 0; j < 16; ++j)
            rowm[j] = 10.0f * nrm[orow + (j >> 2) * 16 + quad * 4 + (j & 3)];
        #pragma unroll
        for (int ni = 0; ni < 4; ++ni) cs[ni] = 10.0f / nrm[ocol + ni * 16 + mfm];
        // single pass: e computed once, acc overwritten in place
        float rs[16] = {};
        float mx = -1e30f;
        #pragma unroll
        for (int ni = 0; ni < 4; ++ni)
            #pragma unroll
            for (int mi = 0; mi < 4; ++mi)
                #pragma unroll
                for (int r = 0; r < 4; ++r) {
                    float lg = acc[mi][ni][r] * cs[ni] - rowm[mi * 4 + r];
                    mx = fmaxf(mx, lg);
                    float e = __expf(lg);
                    acc[mi][ni][r] = e;
                    rs[mi * 4 + r] += e;
                }
        #pragma unroll
        for (int off = 32; off; off >>= 1) mx = fmaxf(mx, __shfl_xor(mx, off));
        if (lane == 0) sred[w] = mx;
        __syncthreads();
        float bmax = fmaxf(fmaxf(sred[0], sred[1]), fmaxf(sred[2], sred[3]));
        int nz = bmax > ZLOG;
        if (nz) {
            #pragma unroll
            for (int ni = 0; ni < 4; ++ni) {
                int col = ocol + ni * 16 + mfm;
                #pragma unroll
                for (int mi = 0; mi < 4; ++mi)
                    #pragma unroll
                    for (int r = 0; r < 4; ++r) {
                        int row = orow + mi * 16 + quad * 4 + r;
                        Eo[(size_t)row * ldc + col] = (f16)acc[mi][ni][r];
                    }
            }
            #pragma unroll
            for (int j = 0; j < 16; ++j) {
                float v = rs[j];
                v += __shfl_xor(v, 1); v += __shfl_xor(v, 2);
                v += __shfl_xor(v, 4); v += __shfl_xor(v, 8);
                if (mfm == 0)
                    atomicAdd(&rowsum[orow + (j >> 2) * 16 + quad * 4 + (j & 3)], v);
            }
        }
        if (tid == 0) flags[by * 32 + bx] = nz;
    } else {
        f16* Oo = outbase + (size_t)bz * ((size_t)E2 * L_);
        #pragma unroll
        for (int mi = 0; mi < 4; ++mi) {
            #pragma unroll
            for (int r = 0; r < 4; ++r) {
                int row = orow + mi * 16 + quad * 4 + r;
                #pragma unroll
                for (int ni = 0; ni < 4; ++ni)
                    Oo[(size_t)row * ldc + ocol + ni * 16 + mfm] = (f16)acc[mi][ni][r];
            }
        }
    }
}

// ---------------- conv_transpose overlap-add gather on OPT[s][e][p] layout, batched ----------------
__global__ __launch_bounds__(256) void gather_kernel(const f16* __restrict__ OPT_g,
                                                     const float* __restrict__ rowsum_g,
                                                     float* __restrict__ out_g) {
    int ls = blockIdx.y;
    const f16* OPT = OPT_g + (size_t)ls * ((size_t)KSPLIT * E2 * L_);
    const float* rowsum = rowsum_g + (size_t)ls * L_;
    float* out_b = out_g + (size_t)ls * (C_ * H_ * W_);
    int idx = blockIdx.x * 256 + threadIdx.x;
    if (idx >= C_ * H_ * W_) return;
    int X = idx & 127, Y = (idx >> 7) & 127, c = idx >> 14;
    int kyp = (Y + 1) & 1;
    int kxp = (X + 1) & 1;
    float sum = 0.f;
    #pragma unroll
    for (int ky = kyp; ky < 4; ky += 2) {
        int py = (Y + 1 - ky) >> 1;
        if ((unsigned)py >= 64u) continue;
        #pragma unroll
        for (int kx = kxp; kx < 4; kx += 2) {
            int px = (X + 1 - kx) >> 1;
            if ((unsigned)px >= 64u) continue;
            int p = py * 64 + px;
            int e = c * 16 + ky * 4 + kx;
            float v = 0.f;
            #pragma unroll
            for (int s = 0; s < KSPLIT; ++s)
                v += (float)OPT[((size_t)s * E2 + e) * L_ + p];
            sum += v * __builtin_amdgcn_rcpf(rowsum[p]);
        }
    }
    out_b[idx] = 0.25f * sum;
}

extern "C" void kernel_launch(void* const* d_in, const int* in_sizes, int n_in,
                              void* d_out, int out_size, void* d_ws, size_t ws_size,
                              hipStream_t stream) {
    const float* bg = (const float*)d_in[0];
    const float* fg = (const float*)d_in[1];
    float* out = (float*)d_out;
    char* w8 = (char*)d_ws;

    // fixed workspace region (bytes)
    float* fgs        = (float*)(w8);                 //  4,194,304
    f16*   P_all      = (f16*)  (w8 + 4194304);       // 18,874,368
    float* nrm        = (float*)(w8 + 23068672);      //     65,536
    float* rowsum_all = (float*)(w8 + 23134208);      //     65,536 (B_ x L_)
    int*   flags      = (int*)  (w8 + 23199744);      //     16,384 (B_ x 32x32 tile flags)
    const size_t base = 23216128;

    // per-sample buffers: VT 8 MiB + Eb 32 MiB + OPT 32 MiB = 72 MiB.
    // batch as many samples per launch round as the workspace allows:
    // nb=4 -> 325.2 MB total, nb=2 -> 174.2 MB (proven fits), nb=1 -> 98.7 MB.
    const size_t perVT  = (size_t)E2 * L_ * 2;        //  8,388,608
    const size_t perEb  = (size_t)L_ * L_ * 2;        // 33,554,432
    const size_t perOPT = (size_t)KSPLIT * E2 * L_ * 2; // 33,554,432
    const size_t per = perVT + perEb + perOPT;
    int nb = 1;
    if (ws_size >= base + 4 * per) nb = 4;
    else if (ws_size >= base + 2 * per) nb = 2;

    f16* VT  = (f16*)(w8 + base);
    f16* Eb  = (f16*)(w8 + base + (size_t)nb * perVT);
    f16* OPT = (f16*)(w8 + base + (size_t)nb * (perVT + perEb));

    resize_kernel<<<(B_ * C_ * HS * WS) / 256, 256, 0, stream>>>(fg, fgs);
    patch_kernel<<<dim3((L_ * K1) / 256, B_), 256, 0, stream>>>(fgs, P_all);
    norm_kernel<<<dim3(L_, B_), 64, 0, stream>>>(P_all, nrm);
    hipMemsetAsync(rowsum_all, 0, (size_t)B_ * L_ * sizeof(float), stream);

    for (int g = 0; g < B_; g += nb) {
        const f16* P_g     = P_all + (size_t)g * L_ * K1;
        const float* nrm_g = nrm + (size_t)g * L_;
        float* rowsum_g    = rowsum_all + (size_t)g * L_;
        int* flags_g       = flags + g * 1024;

        v_kernel<<<dim3((L_ * E2) / 256, nb), 256, 0, stream>>>(
            bg + (size_t)g * C_ * H_ * W_, VT);

        // E[p,l] = exp(10*<P_p,P_l>/nrm[l] - 10*nrm[p]); rowsum[p] += E; tile flags
        mfma_gemm<1><<<dim3(1024, nb), 256, 0, stream>>>(
            P_g, (size_t)L_ * K1, P_g, (size_t)L_ * K1,
            K1, K1, K1, Eb, (size_t)L_ * L_, L_,
            nrm_g, rowsum_g, flags_g);

        // OPT_z[e,p] = sum_{l in slice z} VT[e,l] * E[p,l]  (skips zero E-tiles)
        mfma_gemm<0><<<dim3(1024, nb), 256, 0, stream>>>(
            VT, (size_t)E2 * L_, Eb, (size_t)L_ * L_,
            L_, L_, L_ / KSPLIT, OPT, (size_t)KSPLIT * E2 * L_, L_,
            nullptr, nullptr, flags_g);

        gather_kernel<<<dim3((C_ * H_ * W_) / 256, nb), 256, 0, stream>>>(
            OPT, rowsum_g, out + (size_t)g * C_ * H_ * W_);
    }
}

// Round 3
// 236.082 us; speedup vs baseline: 1.5501x; 1.3964x over previous
//
#include <hip/hip_runtime.h>
#include <hip/hip_bf16.h>
#include <math.h>

#define B_  4
#define C_  64
#define H_  128
#define W_  128
#define HS  64
#define WS  64
#define L_  4096
#define K1  576
#define E2  1024
#define KSPLIT 1
// f16 subnormal floor is 2^-24 (logit -16.635); values below 2^-25 (-17.33) cast
// to exactly 0. Flag threshold -17.5 is conservative: no nonzero f16 is missed.
#define ZLOG (-17.5f)

typedef _Float16 f16;
typedef f16 f16x8 __attribute__((ext_vector_type(8)));
typedef float f32x4 __attribute__((ext_vector_type(4)));

__device__ __forceinline__ void gload16(const void* g, void* l) {
    __builtin_amdgcn_global_load_lds(
        (const __attribute__((address_space(1))) unsigned int*)g,
        (__attribute__((address_space(3))) unsigned int*)l, 16, 0, 0);
}

// swizzled f16 index into a 128x128 LDS tile: 16B chunk XOR'd by row&7
// (write and readback use the same mapping -> bijective, conflict-reduced)
__device__ __forceinline__ int swz(int r, int c) {
    return r * 128 + ((((c >> 3) ^ (r & 7)) << 3) | (c & 7));
}

// ---------------- bilinear resize 128->64, align_corners ----------------
__global__ __launch_bounds__(256) void resize_kernel(const float* __restrict__ fg,
                                                     float* __restrict__ fgs) {
    int idx = blockIdx.x * 256 + threadIdx.x;
    if (idx >= B_ * C_ * HS * WS) return;
    int j = idx & 63, i = (idx >> 6) & 63, bc = idx >> 12;
    const float sc = 127.0f / 63.0f;
    float yf = i * sc, xf = j * sc;
    int y0 = (int)floorf(yf); if (y0 > 127) y0 = 127;
    int x0 = (int)floorf(xf); if (x0 > 127) x0 = 127;
    int y1 = min(y0 + 1, 127), x1 = min(x0 + 1, 127);
    float wy = yf - (float)y0, wx = xf - (float)x0;
    const float* p = fg + (size_t)bc * (H_ * W_);
    float a = p[y0 * W_ + x0], b = p[y0 * W_ + x1];
    float c = p[y1 * W_ + x0], d = p[y1 * W_ + x1];
    float t0 = a * (1.f - wy) + c * wy;
    float t1 = b * (1.f - wy) + d * wy;
    fgs[idx] = t0 * (1.f - wx) + t1 * wx;
}

// ---------------- P[l,k] f16 patches (3x3xC, zero pad 1), batched ----------------
__global__ __launch_bounds__(256) void patch_kernel(const float* __restrict__ fgs,
                                                    f16* __restrict__ P_all) {
    int idx = blockIdx.x * 256 + threadIdx.x;
    int b = blockIdx.y;
    int k = idx % K1, l = idx / K1;
    int c = k / 9, r = k % 9;
    int dy = r / 3, dx = r % 3;
    int ly = l >> 6, lx = l & 63;
    int y = ly - 1 + dy, x = lx - 1 + dx;
    float v = 0.f;
    if ((unsigned)y < 64u && (unsigned)x < 64u)
        v = fgs[((size_t)b * C_ + c) * (HS * WS) + y * WS + x];
    P_all[(size_t)b * L_ * K1 + idx] = (f16)v;
}

// ---------------- norms of f16 patch rows (fp32 accumulate), batched ----------------
__global__ __launch_bounds__(64) void norm_kernel(const f16* __restrict__ P_all,
                                                  float* __restrict__ nrm_all) {
    int l = blockIdx.x, b = blockIdx.y, t = threadIdx.x;
    const f16* row = P_all + ((size_t)b * L_ + l) * K1;
    float s = 0.f;
    for (int k = t; k < K1; k += 64) { float v = (float)row[k]; s = fmaf(v, v, s); }
    #pragma unroll
    for (int off = 32; off; off >>= 1) s += __shfl_down(s, off);
    if (t == 0) nrm_all[b * L_ + l] = fmaxf(sqrtf(s), 1e-4f);
}

// ---------------- VT[e,l] f16 : transposed 4x4xC background patches, batched over grid.y ----------------
__global__ __launch_bounds__(256) void v_kernel(const float* __restrict__ bg_g,
                                                f16* __restrict__ VT_g) {
    int ls = blockIdx.y;
    const float* bg_b = bg_g + (size_t)ls * (C_ * H_ * W_);
    f16* VT = VT_g + (size_t)ls * ((size_t)E2 * L_);
    int idx = blockIdx.x * 256 + threadIdx.x;
    int l = idx & 4095, e = idx >> 12;
    int c = e >> 4, r = e & 15;
    int ky = r >> 2, kx = r & 3;
    int ly = l >> 6, lx = l & 63;
    int by = 2 * ly - 1 + ky, bx = 2 * lx - 1 + kx;
    float v = 0.f;
    if ((unsigned)by < 128u && (unsigned)bx < 128u)
        v = bg_b[(size_t)c * (H_ * W_) + by * W_ + bx];
    VT[idx] = (f16)v;
}

// next flag-valid K position (64-elem chunk granularity, flags per 128)
__device__ __forceinline__ int nextk(int kn, int kLen, unsigned long long mask) {
    while (kn < kLen) {
        int t = kn >> 7;
        if (mask & (1ull << t)) return kn;
        unsigned long long m = mask >> t;
        if (!m) return kLen;
        kn = (t + __builtin_ctzll(m)) << 7;
    }
    return kn;
}

// ---------------- MFMA gemm_bt: D[M,N] = A[M,K] * Bt[N,K]^T, batched over grid.y ----------------
// 128x128 tile, 4 waves (2x2 of 64x64), 16x16x32 f16 MFMA, BK=64, 2-phase
// double-buffered pipeline (verified r2), T2 chunk XOR-swizzle (0 conflicts, r1).
// EPI=1 (score, SYMMETRIC): grid enumerates only upper-triangle tile pairs
//   (t1<=t2), 528 blocks/sample. acc = P[t1-rows] . P[t2-rows]^T. Emits
//   E[p,l]=exp(acc*10/nrm[l]-10nrm[p]) for (p in t1, l in t2) AND (off-diag)
//   the transposed tile E[l,p]=exp(acc*10/nrm[p]-10nrm[l]). Max-logit computed
//   BEFORE exp: all-zero tiles (f16-exact) skip exp/stores/atomics. Nonzero
//   tiles staged through a swizzled 128x128 LDS tile -> coalesced dwordx4
//   stores. Per-tile flags for both (t1,t2) and (t2,t1).
// EPI=0 (PV): KSPLIT=1, kLen=4096. Flag row preloaded via __ballot into a
//   32-bit mask; K-loop jumps directly to nonzero E-tiles (~2 chunks/block).
//   Epilogue always stores the (mostly zero) tile via the coalesced LDS path.
template <int EPI>
__global__ __launch_bounds__(256)
void mfma_gemm(const f16* __restrict__ A, size_t sA,
               const f16* __restrict__ Bt, size_t sB,
               int lda, int ldb, int kLen, void* __restrict__ outp, size_t sOut,
               int ldc, const float* __restrict__ nrm, float* __restrict__ rowsum,
               int* __restrict__ flags) {
    // [buf][half][128 rows x 32 cols]; As doubles as the 128x128 f16 store tile
    __shared__ __align__(16) f16 As[2][2][128 * 32];
    __shared__ __align__(16) f16 Bs[2][2][128 * 32];
    __shared__ float sred[8];

    const int ls = blockIdx.y;
    A  += (size_t)ls * sA;
    Bt += (size_t)ls * sB;
    f16* outbase = (f16*)outp + (size_t)ls * sOut;
    if (EPI == 1) { nrm += (size_t)ls * L_; rowsum += (size_t)ls * L_; }
    flags += ls * 1024;

    const int lin = blockIdx.x;
    int bx, by;
    if (EPI == 1) {
        // XCD-chunked triangular decode: 528 pairs, 66 consecutive per XCD
        int p = (lin & 7) * 66 + (lin >> 3);
        int t1 = 0;
        while (p >= 32 - t1) { p -= 32 - t1; ++t1; }
        by = t1; bx = t1 + p;
    } else {
        by = lin & 7; bx = lin >> 3;   // by: e-tile (VT panel/XCD), bx: p-tile
    }

    const int tid = threadIdx.x;
    const int w = tid >> 6, lane = tid & 63;
    const int row0 = by * 128, col0 = bx * 128;

    unsigned long long kmask = ~0ull;
    if (EPI == 0) {
        int f = (lane < 32) ? flags[bx * 32 + lane] : 0;
        kmask = __ballot(f != 0);
    }

    const int srow = w * 32 + (lane >> 2);
    // swizzled source chunk: LDS[row][q] holds global chunk q ^ ((row>>1)&3)
    const int scol = (((lane & 3) ^ ((lane >> 3) & 3)) * 8);
    const f16* gA = A + (size_t)(row0 + srow) * lda + scol;
    const f16* gB = Bt + (size_t)(col0 + srow) * ldb + scol;
    const int l0 = (w * 32) * 32, l1 = (w * 32 + 16) * 32;

    const int wm = w >> 1, wn = w & 1;
    const int mfm = lane & 15, quad = lane >> 4;
    // swizzled read chunk (element offset): undoes the staging permutation
    const int rq = (quad ^ ((mfm >> 1) & 3)) * 8;
    f32x4 acc[4][4] = {};

    int kc = (EPI == 0) ? nextk(0, kLen, kmask) : 0;
    if (kc < kLen) {
        int cur = 0;
        gload16(gA + kc,                         &As[0][0][l0]);
        gload16(gA + kc + (size_t)16 * lda,      &As[0][0][l1]);
        gload16(gA + kc + 32,                    &As[0][1][l0]);
        gload16(gA + kc + 32 + (size_t)16 * lda, &As[0][1][l1]);
        gload16(gB + kc,                         &Bs[0][0][l0]);
        gload16(gB + kc + (size_t)16 * ldb,      &Bs[0][0][l1]);
        gload16(gB + kc + 32,                    &Bs[0][1][l0]);
        gload16(gB + kc + 32 + (size_t)16 * ldb, &Bs[0][1][l1]);
        __syncthreads();
        for (;;) {
            int kn = (EPI == 0) ? nextk(kc + 64, kLen, kmask) : kc + 64;
            if (kn < kLen) {
                const int nxt = cur ^ 1;
                gload16(gA + kn,                         &As[nxt][0][l0]);
                gload16(gA + kn + (size_t)16 * lda,      &As[nxt][0][l1]);
                gload16(gA + kn + 32,                    &As[nxt][1][l0]);
                gload16(gA + kn + 32 + (size_t)16 * lda, &As[nxt][1][l1]);
                gload16(gB + kn,                         &Bs[nxt][0][l0]);
                gload16(gB + kn + (size_t)16 * ldb,      &Bs[nxt][0][l1]);
                gload16(gB + kn + 32,                    &Bs[nxt][1][l0]);
                gload16(gB + kn + 32 + (size_t)16 * ldb, &Bs[nxt][1][l1]);
            }
            #pragma unroll
            for (int h = 0; h < 2; ++h) {
                f16x8 af[4], bf[4];
                #pragma unroll
                for (int mi = 0; mi < 4; ++mi)
                    af[mi] = *(const f16x8*)&As[cur][h][(wm * 64 + mi * 16 + mfm) * 32 + rq];
                #pragma unroll
                for (int ni = 0; ni < 4; ++ni)
                    bf[ni] = *(const f16x8*)&Bs[cur][h][(wn * 64 + ni * 16 + mfm) * 32 + rq];
                __builtin_amdgcn_s_setprio(1);
                #pragma unroll
                for (int mi = 0; mi < 4; ++mi)
                    #pragma unroll
                    for (int ni = 0; ni < 4; ++ni)
                        acc[mi][ni] = __builtin_amdgcn_mfma_f32_16x16x32_f16(
                            af[mi], bf[ni], acc[mi][ni], 0, 0, 0);
                __builtin_amdgcn_s_setprio(0);
            }
            __syncthreads();
            cur ^= 1;
            kc = kn;
            if (kc >= kLen) break;
        }
    }

    const int orow = row0 + wm * 64;   // global row of this wave's quadrant
    const int ocol = col0 + wn * 64;   // global col
    f16* st = &As[0][0][0];            // 128x128 f16 tile (32 KB)

    if (EPI == 1) {
        f16* Eo = outbase;
        const bool offd = (by != bx);
        float rowm[16], cs[4], csr[16], cm2[4];
        #pragma unroll
        for (int j = 0; j < 16; ++j) {
            float n = nrm[orow + (j >> 2) * 16 + quad * 4 + (j & 3)];
            rowm[j] = 10.0f * n; csr[j] = 10.0f / n;
        }
        #pragma unroll
        for (int ni = 0; ni < 4; ++ni) {
            float n = nrm[ocol + ni * 16 + mfm];
            cs[ni] = 10.0f / n; cm2[ni] = 10.0f * n;
        }
        // max-logit pass (no exp): tile1 = E[p,l], tile2 = E[l,p] (off-diag)
        float mx1 = -1e30f, mx2 = -1e30f;
        #pragma unroll
        for (int ni = 0; ni < 4; ++ni)
            #pragma unroll
            for (int mi = 0; mi < 4; ++mi)
                #pragma unroll
                for (int r = 0; r < 4; ++r) {
                    float a = acc[mi][ni][r];
                    mx1 = fmaxf(mx1, a * cs[ni] - rowm[mi * 4 + r]);
                    mx2 = fmaxf(mx2, a * csr[mi * 4 + r] - cm2[ni]);
                }
        #pragma unroll
        for (int off = 32; off; off >>= 1) {
            mx1 = fmaxf(mx1, __shfl_xor(mx1, off));
            mx2 = fmaxf(mx2, __shfl_xor(mx2, off));
        }
        if (lane == 0) { sred[w] = mx1; sred[4 + w] = mx2; }
        __syncthreads();
        float b1 = fmaxf(fmaxf(sred[0], sred[1]), fmaxf(sred[2], sred[3]));
        float b2 = fmaxf(fmaxf(sred[4], sred[5]), fmaxf(sred[6], sred[7]));
        int nz1 = b1 > ZLOG;
        int nz2 = offd && (b2 > ZLOG);
        if (nz1) {
            float rs[16] = {};
            #pragma unroll
            for (int ni = 0; ni < 4; ++ni)
                #pragma unroll
                for (int mi = 0; mi < 4; ++mi)
                    #pragma unroll
                    for (int r = 0; r < 4; ++r) {
                        float e = __expf(acc[mi][ni][r] * cs[ni] - rowm[mi * 4 + r]);
                        rs[mi * 4 + r] += e;
                        st[swz(wm * 64 + mi * 16 + quad * 4 + r,
                               wn * 64 + ni * 16 + mfm)] = (f16)e;
                    }
            __syncthreads();
            #pragma unroll
            for (int it = 0; it < 8; ++it) {
                int chunk = it * 256 + tid;
                int row = chunk >> 4, c16 = chunk & 15;
                f16x8 v = *(const f16x8*)&st[row * 128 + ((c16 ^ (row & 7)) << 3)];
                *(f16x8*)&Eo[(size_t)(row0 + row) * ldc + col0 + c16 * 8] = v;
            }
            #pragma unroll
            for (int j = 0; j < 16; ++j) {
                float v = rs[j];
                v += __shfl_xor(v, 1); v += __shfl_xor(v, 2);
                v += __shfl_xor(v, 4); v += __shfl_xor(v, 8);
                if (mfm == 0)
                    atomicAdd(&rowsum[orow + (j >> 2) * 16 + quad * 4 + (j & 3)], v);
            }
        }
        if (nz2) {
            __syncthreads();   // protect st from tile1 readback
            float rs2[4] = {};
            #pragma unroll
            for (int ni = 0; ni < 4; ++ni)
                #pragma unroll
                for (int mi = 0; mi < 4; ++mi)
                    #pragma unroll
                    for (int r = 0; r < 4; ++r) {
                        float e = __expf(acc[mi][ni][r] * csr[mi * 4 + r] - cm2[ni]);
                        rs2[ni] += e;
                        st[swz(wn * 64 + ni * 16 + mfm,
                               wm * 64 + mi * 16 + quad * 4 + r)] = (f16)e;
                    }
            __syncthreads();
            #pragma unroll
            for (int it = 0; it < 8; ++it) {
                int chunk = it * 256 + tid;
                int row = chunk >> 4, c16 = chunk & 15;
                f16x8 v = *(const f16x8*)&st[row * 128 + ((c16 ^ (row & 7)) << 3)];
                *(f16x8*)&Eo[(size_t)(col0 + row) * ldc + row0 + c16 * 8] = v;
            }
            #pragma unroll
            for (int ni = 0; ni < 4; ++ni) {
                float v = rs2[ni];
                v += __shfl_xor(v, 16); v += __shfl_xor(v, 32);
                if (quad == 0)
                    atomicAdd(&rowsum[ocol + ni * 16 + mfm], v);
            }
        }
        if (tid == 0) {
            flags[by * 32 + bx] = nz1;
            if (offd) flags[bx * 32 + by] = nz2;
        }
    } else {
        // coalesced store of the (often zero) 128x128 output tile
        #pragma unroll
        for (int ni = 0; ni < 4; ++ni)
            #pragma unroll
            for (int mi = 0; mi < 4; ++mi)
                #pragma unroll
                for (int r = 0; r < 4; ++r)
                    st[swz(wm * 64 + mi * 16 + quad * 4 + r,
                           wn * 64 + ni * 16 + mfm)] = (f16)acc[mi][ni][r];
        __syncthreads();
        f16* base = outbase + (size_t)row0 * ldc + col0;
        #pragma unroll
        for (int it = 0; it < 8; ++it) {
            int chunk = it * 256 + tid;
            int row = chunk >> 4, c16 = chunk & 15;
            f16x8 v = *(const f16x8*)&st[row * 128 + ((c16 ^ (row & 7)) << 3)];
            *(f16x8*)&base[(size_t)row * ldc + c16 * 8] = v;
        }
    }
}

// ---------------- conv_transpose overlap-add gather on OPT[e][p] layout, batched ----------------
__global__ __launch_bounds__(256) void gather_kernel(const f16* __restrict__ OPT_g,
                                                     const float* __restrict__ rowsum_g,
                                                     float* __restrict__ out_g) {
    int ls = blockIdx.y;
    const f16* OPT = OPT_g + (size_t)ls * ((size_t)KSPLIT * E2 * L_);
    const float* rowsum = rowsum_g + (size_t)ls * L_;
    float* out_b = out_g + (size_t)ls * (C_ * H_ * W_);
    int idx = blockIdx.x * 256 + threadIdx.x;
    if (idx >= C_ * H_ * W_) return;
    int X = idx & 127, Y = (idx >> 7) & 127, c = idx >> 14;
    int kyp = (Y + 1) & 1;
    int kxp = (X + 1) & 1;
    float sum = 0.f;
    #pragma unroll
    for (int ky = kyp; ky < 4; ky += 2) {
        int py = (Y + 1 - ky) >> 1;
        if ((unsigned)py >= 64u) continue;
        #pragma unroll
        for (int kx = kxp; kx < 4; kx += 2) {
            int px = (X + 1 - kx) >> 1;
            if ((unsigned)px >= 64u) continue;
            int p = py * 64 + px;
            int e = c * 16 + ky * 4 + kx;
            float v = 0.f;
            #pragma unroll
            for (int s = 0; s < KSPLIT; ++s)
                v += (float)OPT[((size_t)s * E2 + e) * L_ + p];
            sum += v * __builtin_amdgcn_rcpf(rowsum[p]);
        }
    }
    out_b[idx] = 0.25f * sum;
}

extern "C" void kernel_launch(void* const* d_in, const int* in_sizes, int n_in,
                              void* d_out, int out_size, void* d_ws, size_t ws_size,
                              hipStream_t stream) {
    const float* bg = (const float*)d_in[0];
    const float* fg = (const float*)d_in[1];
    float* out = (float*)d_out;
    char* w8 = (char*)d_ws;

    // fixed workspace region (bytes)
    float* fgs        = (float*)(w8);                 //  4,194,304
    f16*   P_all      = (f16*)  (w8 + 4194304);       // 18,874,368
    float* nrm        = (float*)(w8 + 23068672);      //     65,536
    float* rowsum_all = (float*)(w8 + 23134208);      //     65,536 (B_ x L_)
    int*   flags      = (int*)  (w8 + 23199744);      //     16,384 (B_ x 32x32 tile flags)
    const size_t base = 23216128;

    // per-sample buffers: VT 8 MiB + Eb 32 MiB + OPT 8 MiB = 48 MiB.
    // nb=4 -> 224.5 MB, nb=2 -> 123.9 MB (fits: r2 proved >=174 MB), nb=1 -> 73.5 MB
    const size_t perVT  = (size_t)E2 * L_ * 2;          //  8,388,608
    const size_t perEb  = (size_t)L_ * L_ * 2;          // 33,554,432
    const size_t perOPT = (size_t)KSPLIT * E2 * L_ * 2; //  8,388,608
    const size_t per = perVT + perEb + perOPT;
    int nb = 1;
    if (ws_size >= base + 4 * per) nb = 4;
    else if (ws_size >= base + 2 * per) nb = 2;

    f16* VT  = (f16*)(w8 + base);
    f16* Eb  = (f16*)(w8 + base + (size_t)nb * perVT);
    f16* OPT = (f16*)(w8 + base + (size_t)nb * (perVT + perEb));

    resize_kernel<<<(B_ * C_ * HS * WS) / 256, 256, 0, stream>>>(fg, fgs);
    patch_kernel<<<dim3((L_ * K1) / 256, B_), 256, 0, stream>>>(fgs, P_all);
    norm_kernel<<<dim3(L_, B_), 64, 0, stream>>>(P_all, nrm);
    hipMemsetAsync(rowsum_all, 0, (size_t)B_ * L_ * sizeof(float), stream);

    for (int g = 0; g < B_; g += nb) {
        const f16* P_g     = P_all + (size_t)g * L_ * K1;
        const float* nrm_g = nrm + (size_t)g * L_;
        float* rowsum_g    = rowsum_all + (size_t)g * L_;
        int* flags_g       = flags + g * 1024;

        v_kernel<<<dim3((L_ * E2) / 256, nb), 256, 0, stream>>>(
            bg + (size_t)g * C_ * H_ * W_, VT);

        // E (both triangles from upper-triangle gram tiles) + rowsum + flags
        mfma_gemm<1><<<dim3(528, nb), 256, 0, stream>>>(
            P_g, (size_t)L_ * K1, P_g, (size_t)L_ * K1,
            K1, K1, K1, Eb, (size_t)L_ * L_, L_,
            nrm_g, rowsum_g, flags_g);

        // OPT[e,p] = sum_l VT[e,l] * E[p,l]  (mask-driven tile skip)
        mfma_gemm<0><<<dim3(256, nb), 256, 0, stream>>>(
            VT, (size_t)E2 * L_, Eb, (size_t)L_ * L_,
            L_, L_, L_, OPT, (size_t)KSPLIT * E2 * L_, L_,
            nullptr, nullptr, flags_g);

        gather_kernel<<<dim3((C_ * H_ * W_) / 256, nb), 256, 0, stream>>>(
            OPT, rowsum_g, out + (size_t)g * C_ * H_ * W_);
    }
}

// Round 4
// 232.793 us; speedup vs baseline: 1.5720x; 1.0141x over previous
//
#include <hip/hip_runtime.h>
#include <hip/hip_bf16.h>
#include <math.h>

#define B_  4
#define C_  64
#define H_  128
#define W_  128
#define HS  64
#define WS  64
#define L_  4096
#define K1  576
#define E2  1024
#define KSPLIT 1
// f16 subnormal floor is 2^-24 (logit -16.635); values below 2^-25 (-17.33) cast
// to exactly 0. Flag threshold -17.5 is conservative: no nonzero f16 is missed.
#define ZLOG (-17.5f)

typedef _Float16 f16;
typedef f16 f16x8 __attribute__((ext_vector_type(8)));
typedef float f32x4 __attribute__((ext_vector_type(4)));

__device__ __forceinline__ void gload16(const void* g, void* l) {
    __builtin_amdgcn_global_load_lds(
        (const __attribute__((address_space(1))) unsigned int*)g,
        (__attribute__((address_space(3))) unsigned int*)l, 16, 0, 0);
}

// swizzled f16 index into a 128x128 LDS tile: 16B chunk XOR'd by row&7
// (write and readback use the same mapping -> bijective, conflict-reduced)
__device__ __forceinline__ int swz(int r, int c) {
    return r * 128 + ((((c >> 3) ^ (r & 7)) << 3) | (c & 7));
}

// ---------------- bilinear resize 128->64, align_corners ----------------
__global__ __launch_bounds__(256) void resize_kernel(const float* __restrict__ fg,
                                                     float* __restrict__ fgs) {
    int idx = blockIdx.x * 256 + threadIdx.x;
    if (idx >= B_ * C_ * HS * WS) return;
    int j = idx & 63, i = (idx >> 6) & 63, bc = idx >> 12;
    const float sc = 127.0f / 63.0f;
    float yf = i * sc, xf = j * sc;
    int y0 = (int)floorf(yf); if (y0 > 127) y0 = 127;
    int x0 = (int)floorf(xf); if (x0 > 127) x0 = 127;
    int y1 = min(y0 + 1, 127), x1 = min(x0 + 1, 127);
    float wy = yf - (float)y0, wx = xf - (float)x0;
    const float* p = fg + (size_t)bc * (H_ * W_);
    float a = p[y0 * W_ + x0], b = p[y0 * W_ + x1];
    float c = p[y1 * W_ + x0], d = p[y1 * W_ + x1];
    float t0 = a * (1.f - wy) + c * wy;
    float t1 = b * (1.f - wy) + d * wy;
    fgs[idx] = t0 * (1.f - wx) + t1 * wx;
}

// ---------------- P[l,k] f16 patches (3x3xC, zero pad 1), batched ----------------
__global__ __launch_bounds__(256) void patch_kernel(const float* __restrict__ fgs,
                                                    f16* __restrict__ P_all) {
    int idx = blockIdx.x * 256 + threadIdx.x;
    int b = blockIdx.y;
    int k = idx % K1, l = idx / K1;
    int c = k / 9, r = k % 9;
    int dy = r / 3, dx = r % 3;
    int ly = l >> 6, lx = l & 63;
    int y = ly - 1 + dy, x = lx - 1 + dx;
    float v = 0.f;
    if ((unsigned)y < 64u && (unsigned)x < 64u)
        v = fgs[((size_t)b * C_ + c) * (HS * WS) + y * WS + x];
    P_all[(size_t)b * L_ * K1 + idx] = (f16)v;
}

// ---------------- norms of f16 patch rows (fp32 accumulate), batched ----------------
__global__ __launch_bounds__(64) void norm_kernel(const f16* __restrict__ P_all,
                                                  float* __restrict__ nrm_all) {
    int l = blockIdx.x, b = blockIdx.y, t = threadIdx.x;
    const f16* row = P_all + ((size_t)b * L_ + l) * K1;
    float s = 0.f;
    for (int k = t; k < K1; k += 64) { float v = (float)row[k]; s = fmaf(v, v, s); }
    #pragma unroll
    for (int off = 32; off; off >>= 1) s += __shfl_down(s, off);
    if (t == 0) nrm_all[b * L_ + l] = fmaxf(sqrtf(s), 1e-4f);
}

// ---------------- VT[e,l] f16 : transposed 4x4xC background patches, batched over grid.y ----------------
__global__ __launch_bounds__(256) void v_kernel(const float* __restrict__ bg_g,
                                                f16* __restrict__ VT_g) {
    int ls = blockIdx.y;
    const float* bg_b = bg_g + (size_t)ls * (C_ * H_ * W_);
    f16* VT = VT_g + (size_t)ls * ((size_t)E2 * L_);
    int idx = blockIdx.x * 256 + threadIdx.x;
    int l = idx & 4095, e = idx >> 12;
    int c = e >> 4, r = e & 15;
    int ky = r >> 2, kx = r & 3;
    int ly = l >> 6, lx = l & 63;
    int by = 2 * ly - 1 + ky, bx = 2 * lx - 1 + kx;
    float v = 0.f;
    if ((unsigned)by < 128u && (unsigned)bx < 128u)
        v = bg_b[(size_t)c * (H_ * W_) + by * W_ + bx];
    VT[idx] = (f16)v;
}

// next flag-valid K position (64-elem chunk granularity, flags per 128)
__device__ __forceinline__ int nextk(int kn, int kLen, unsigned long long mask) {
    while (kn < kLen) {
        int t = kn >> 7;
        if (mask & (1ull << t)) return kn;
        unsigned long long m = mask >> t;
        if (!m) return kLen;
        kn = (t + __builtin_ctzll(m)) << 7;
    }
    return kn;
}

// ---------------- MFMA gemm_bt: D[M,N] = A[M,K] * Bt[N,K]^T ----------------
// 128x128 tile, 4 waves (2x2 of 64x64), 16x16x32 f16 MFMA, BK=64, 2-phase
// double-buffered pipeline (r2), T2 chunk XOR-swizzle (0 conflicts, r1).
// L2-LOCALITY SCHEDULE (r4): 1-D grid, lin&7 = XCD. Each sample's work is
// partitioned into compact regions that FIT a 4-MiB XCD L2, and each region is
// pinned to contiguous per-XCD slots:
//   EPI=1: per sample, the 32x32 upper-triangle (528 pairs) splits into
//     rr=0: T(16) over tiles [0,16)         -> 136 pairs, 16 panels (2.35 MB)
//     rr=1: T(16) over tiles [16,32)        -> 136 pairs, 16 panels (2.35 MB)
//     rr=2: square t1 in [0,16) x t2 [16,24)-> 128 pairs, 24 panels (3.5 MB)
//     rr=3: square t1 in [0,16) x t2 [24,32)-> 128 pairs, 24 panels (3.5 MB)
//   region id R = 4*ls + rr; global slot s = R*136 + q; XCD x owns the
//   contiguous slot range [x*S, (x+1)*S), S = gridDim.x/8. (nb=2: exactly one
//   region per XCD, samples split across XCD halves.)
//   EPI=0: slot G = xcd*S + idx; ls = G>>8, by = (G>>5)&7, bx = G&31 -> each
//   XCD owns a few VT e-panels (1 MiB each) of ONE sample.
// EPI=1 epilogue (unchanged r3): both E triangles from one gram tile, max-logit
//   pre-pass skips exp/stores for all-zero tiles (f16-exact), coalesced LDS-
//   staged stores, rowsum atomics, per-tile flags.
// EPI=0 (PV): ballot flag mask, K-loop jumps to nonzero E-tiles only.
template <int EPI>
__global__ __launch_bounds__(256)
void mfma_gemm(const f16* __restrict__ A, size_t sA,
               const f16* __restrict__ Bt, size_t sB,
               int lda, int ldb, int kLen, void* __restrict__ outp, size_t sOut,
               int ldc, const float* __restrict__ nrm, float* __restrict__ rowsum,
               int* __restrict__ flags) {
    // [buf][half][128 rows x 32 cols]; As doubles as the 128x128 f16 store tile
    __shared__ __align__(16) f16 As[2][2][128 * 32];
    __shared__ __align__(16) f16 Bs[2][2][128 * 32];
    __shared__ float sred[8];

    const int lin = blockIdx.x;
    const int S = gridDim.x >> 3;
    int bx, by, ls;
    if (EPI == 1) {
        int s = (lin & 7) * S + (lin >> 3);
        int R = s / 136, q = s - R * 136;
        ls = R >> 2;
        int rr = R & 3;
        if (rr < 2) {
            int a = 0;
            while (q >= 16 - a) { q -= 16 - a; ++a; }
            by = a + (rr << 4); bx = a + q + (rr << 4);
        } else {
            if (q >= 128) return;   // idle filler slot
            by = q & 15; bx = 16 + ((rr & 1) << 3) + (q >> 4);
        }
    } else {
        int G = (lin & 7) * S + (lin >> 3);
        ls = G >> 8;
        by = (G >> 5) & 7; bx = G & 31;   // by: e-tile, bx: p-tile
    }

    A  += (size_t)ls * sA;
    Bt += (size_t)ls * sB;
    f16* outbase = (f16*)outp + (size_t)ls * sOut;
    if (EPI == 1) { nrm += (size_t)ls * L_; rowsum += (size_t)ls * L_; }
    flags += ls * 1024;

    const int tid = threadIdx.x;
    const int w = tid >> 6, lane = tid & 63;
    const int row0 = by * 128, col0 = bx * 128;

    unsigned long long kmask = ~0ull;
    if (EPI == 0) {
        int f = (lane < 32) ? flags[bx * 32 + lane] : 0;
        kmask = __ballot(f != 0);
    }

    const int srow = w * 32 + (lane >> 2);
    // swizzled source chunk: LDS[row][q] holds global chunk q ^ ((row>>1)&3)
    const int scol = (((lane & 3) ^ ((lane >> 3) & 3)) * 8);
    const f16* gA = A + (size_t)(row0 + srow) * lda + scol;
    const f16* gB = Bt + (size_t)(col0 + srow) * ldb + scol;
    const int l0 = (w * 32) * 32, l1 = (w * 32 + 16) * 32;

    const int wm = w >> 1, wn = w & 1;
    const int mfm = lane & 15, quad = lane >> 4;
    // swizzled read chunk (element offset): undoes the staging permutation
    const int rq = (quad ^ ((mfm >> 1) & 3)) * 8;
    f32x4 acc[4][4] = {};

    int kc = (EPI == 0) ? nextk(0, kLen, kmask) : 0;
    if (kc < kLen) {
        int cur = 0;
        gload16(gA + kc,                         &As[0][0][l0]);
        gload16(gA + kc + (size_t)16 * lda,      &As[0][0][l1]);
        gload16(gA + kc + 32,                    &As[0][1][l0]);
        gload16(gA + kc + 32 + (size_t)16 * lda, &As[0][1][l1]);
        gload16(gB + kc,                         &Bs[0][0][l0]);
        gload16(gB + kc + (size_t)16 * ldb,      &Bs[0][0][l1]);
        gload16(gB + kc + 32,                    &Bs[0][1][l0]);
        gload16(gB + kc + 32 + (size_t)16 * ldb, &Bs[0][1][l1]);
        __syncthreads();
        for (;;) {
            int kn = (EPI == 0) ? nextk(kc + 64, kLen, kmask) : kc + 64;
            if (kn < kLen) {
                const int nxt = cur ^ 1;
                gload16(gA + kn,                         &As[nxt][0][l0]);
                gload16(gA + kn + (size_t)16 * lda,      &As[nxt][0][l1]);
                gload16(gA + kn + 32,                    &As[nxt][1][l0]);
                gload16(gA + kn + 32 + (size_t)16 * lda, &As[nxt][1][l1]);
                gload16(gB + kn,                         &Bs[nxt][0][l0]);
                gload16(gB + kn + (size_t)16 * ldb,      &Bs[nxt][0][l1]);
                gload16(gB + kn + 32,                    &Bs[nxt][1][l0]);
                gload16(gB + kn + 32 + (size_t)16 * ldb, &Bs[nxt][1][l1]);
            }
            #pragma unroll
            for (int h = 0; h < 2; ++h) {
                f16x8 af[4], bf[4];
                #pragma unroll
                for (int mi = 0; mi < 4; ++mi)
                    af[mi] = *(const f16x8*)&As[cur][h][(wm * 64 + mi * 16 + mfm) * 32 + rq];
                #pragma unroll
                for (int ni = 0; ni < 4; ++ni)
                    bf[ni] = *(const f16x8*)&Bs[cur][h][(wn * 64 + ni * 16 + mfm) * 32 + rq];
                __builtin_amdgcn_s_setprio(1);
                #pragma unroll
                for (int mi = 0; mi < 4; ++mi)
                    #pragma unroll
                    for (int ni = 0; ni < 4; ++ni)
                        acc[mi][ni] = __builtin_amdgcn_mfma_f32_16x16x32_f16(
                            af[mi], bf[ni], acc[mi][ni], 0, 0, 0);
                __builtin_amdgcn_s_setprio(0);
            }
            __syncthreads();
            cur ^= 1;
            kc = kn;
            if (kc >= kLen) break;
        }
    }

    const int orow = row0 + wm * 64;   // global row of this wave's quadrant
    const int ocol = col0 + wn * 64;   // global col
    f16* st = &As[0][0][0];            // 128x128 f16 tile (32 KB)

    if (EPI == 1) {
        f16* Eo = outbase;
        const bool offd = (by != bx);
        float rowm[16], cs[4], csr[16], cm2[4];
        #pragma unroll
        for (int j = 0; j < 16; ++j) {
            float n = nrm[orow + (j >> 2) * 16 + quad * 4 + (j & 3)];
            rowm[j] = 10.0f * n; csr[j] = 10.0f / n;
        }
        #pragma unroll
        for (int ni = 0; ni < 4; ++ni) {
            float n = nrm[ocol + ni * 16 + mfm];
            cs[ni] = 10.0f / n; cm2[ni] = 10.0f * n;
        }
        // max-logit pass (no exp): tile1 = E[p,l], tile2 = E[l,p] (off-diag)
        float mx1 = -1e30f, mx2 = -1e30f;
        #pragma unroll
        for (int ni = 0; ni < 4; ++ni)
            #pragma unroll
            for (int mi = 0; mi < 4; ++mi)
                #pragma unroll
                for (int r = 0; r < 4; ++r) {
                    float a = acc[mi][ni][r];
                    mx1 = fmaxf(mx1, a * cs[ni] - rowm[mi * 4 + r]);
                    mx2 = fmaxf(mx2, a * csr[mi * 4 + r] - cm2[ni]);
                }
        #pragma unroll
        for (int off = 32; off; off >>= 1) {
            mx1 = fmaxf(mx1, __shfl_xor(mx1, off));
            mx2 = fmaxf(mx2, __shfl_xor(mx2, off));
        }
        if (lane == 0) { sred[w] = mx1; sred[4 + w] = mx2; }
        __syncthreads();
        float b1 = fmaxf(fmaxf(sred[0], sred[1]), fmaxf(sred[2], sred[3]));
        float b2 = fmaxf(fmaxf(sred[4], sred[5]), fmaxf(sred[6], sred[7]));
        int nz1 = b1 > ZLOG;
        int nz2 = offd && (b2 > ZLOG);
        if (nz1) {
            float rs[16] = {};
            #pragma unroll
            for (int ni = 0; ni < 4; ++ni)
                #pragma unroll
                for (int mi = 0; mi < 4; ++mi)
                    #pragma unroll
                    for (int r = 0; r < 4; ++r) {
                        float e = __expf(acc[mi][ni][r] * cs[ni] - rowm[mi * 4 + r]);
                        rs[mi * 4 + r] += e;
                        st[swz(wm * 64 + mi * 16 + quad * 4 + r,
                               wn * 64 + ni * 16 + mfm)] = (f16)e;
                    }
            __syncthreads();
            #pragma unroll
            for (int it = 0; it < 8; ++it) {
                int chunk = it * 256 + tid;
                int row = chunk >> 4, c16 = chunk & 15;
                f16x8 v = *(const f16x8*)&st[row * 128 + ((c16 ^ (row & 7)) << 3)];
                *(f16x8*)&Eo[(size_t)(row0 + row) * ldc + col0 + c16 * 8] = v;
            }
            #pragma unroll
            for (int j = 0; j < 16; ++j) {
                float v = rs[j];
                v += __shfl_xor(v, 1); v += __shfl_xor(v, 2);
                v += __shfl_xor(v, 4); v += __shfl_xor(v, 8);
                if (mfm == 0)
                    atomicAdd(&rowsum[orow + (j >> 2) * 16 + quad * 4 + (j & 3)], v);
            }
        }
        if (nz2) {
            __syncthreads();   // protect st from tile1 readback
            float rs2[4] = {};
            #pragma unroll
            for (int ni = 0; ni < 4; ++ni)
                #pragma unroll
                for (int mi = 0; mi < 4; ++mi)
                    #pragma unroll
                    for (int r = 0; r < 4; ++r) {
                        float e = __expf(acc[mi][ni][r] * csr[mi * 4 + r] - cm2[ni]);
                        rs2[ni] += e;
                        st[swz(wn * 64 + ni * 16 + mfm,
                               wm * 64 + mi * 16 + quad * 4 + r)] = (f16)e;
                    }
            __syncthreads();
            #pragma unroll
            for (int it = 0; it < 8; ++it) {
                int chunk = it * 256 + tid;
                int row = chunk >> 4, c16 = chunk & 15;
                f16x8 v = *(const f16x8*)&st[row * 128 + ((c16 ^ (row & 7)) << 3)];
                *(f16x8*)&Eo[(size_t)(col0 + row) * ldc + row0 + c16 * 8] = v;
            }
            #pragma unroll
            for (int ni = 0; ni < 4; ++ni) {
                float v = rs2[ni];
                v += __shfl_xor(v, 16); v += __shfl_xor(v, 32);
                if (quad == 0)
                    atomicAdd(&rowsum[ocol + ni * 16 + mfm], v);
            }
        }
        if (tid == 0) {
            flags[by * 32 + bx] = nz1;
            if (offd) flags[bx * 32 + by] = nz2;
        }
    } else {
        // coalesced store of the (often zero) 128x128 output tile
        #pragma unroll
        for (int ni = 0; ni < 4; ++ni)
            #pragma unroll
            for (int mi = 0; mi < 4; ++mi)
                #pragma unroll
                for (int r = 0; r < 4; ++r)
                    st[swz(wm * 64 + mi * 16 + quad * 4 + r,
                           wn * 64 + ni * 16 + mfm)] = (f16)acc[mi][ni][r];
        __syncthreads();
        f16* base = outbase + (size_t)row0 * ldc + col0;
        #pragma unroll
        for (int it = 0; it < 8; ++it) {
            int chunk = it * 256 + tid;
            int row = chunk >> 4, c16 = chunk & 15;
            f16x8 v = *(const f16x8*)&st[row * 128 + ((c16 ^ (row & 7)) << 3)];
            *(f16x8*)&base[(size_t)row * ldc + c16 * 8] = v;
        }
    }
}

// ---------------- conv_transpose overlap-add gather on OPT[e][p] layout, batched ----------------
__global__ __launch_bounds__(256) void gather_kernel(const f16* __restrict__ OPT_g,
                                                     const float* __restrict__ rowsum_g,
                                                     float* __restrict__ out_g) {
    int ls = blockIdx.y;
    const f16* OPT = OPT_g + (size_t)ls * ((size_t)KSPLIT * E2 * L_);
    const float* rowsum = rowsum_g + (size_t)ls * L_;
    float* out_b = out_g + (size_t)ls * (C_ * H_ * W_);
    int idx = blockIdx.x * 256 + threadIdx.x;
    if (idx >= C_ * H_ * W_) return;
    int X = idx & 127, Y = (idx >> 7) & 127, c = idx >> 14;
    int kyp = (Y + 1) & 1;
    int kxp = (X + 1) & 1;
    float sum = 0.f;
    #pragma unroll
    for (int ky = kyp; ky < 4; ky += 2) {
        int py = (Y + 1 - ky) >> 1;
        if ((unsigned)py >= 64u) continue;
        #pragma unroll
        for (int kx = kxp; kx < 4; kx += 2) {
            int px = (X + 1 - kx) >> 1;
            if ((unsigned)px >= 64u) continue;
            int p = py * 64 + px;
            int e = c * 16 + ky * 4 + kx;
            float v = 0.f;
            #pragma unroll
            for (int s = 0; s < KSPLIT; ++s)
                v += (float)OPT[((size_t)s * E2 + e) * L_ + p];
            sum += v * __builtin_amdgcn_rcpf(rowsum[p]);
        }
    }
    out_b[idx] = 0.25f * sum;
}

extern "C" void kernel_launch(void* const* d_in, const int* in_sizes, int n_in,
                              void* d_out, int out_size, void* d_ws, size_t ws_size,
                              hipStream_t stream) {
    const float* bg = (const float*)d_in[0];
    const float* fg = (const float*)d_in[1];
    float* out = (float*)d_out;
    char* w8 = (char*)d_ws;

    // fixed workspace region (bytes)
    float* fgs        = (float*)(w8);                 //  4,194,304
    f16*   P_all      = (f16*)  (w8 + 4194304);       // 18,874,368
    float* nrm        = (float*)(w8 + 23068672);      //     65,536
    float* rowsum_all = (float*)(w8 + 23134208);      //     65,536 (B_ x L_)
    int*   flags      = (int*)  (w8 + 23199744);      //     16,384 (B_ x 32x32 tile flags)
    const size_t base = 23216128;

    // per-sample buffers: VT 8 MiB + Eb 32 MiB + OPT 8 MiB = 48 MiB.
    // nb=4 -> 224.5 MB, nb=2 -> 123.9 MB (fits: proven >=174 MB), nb=1 -> 73.5 MB
    const size_t perVT  = (size_t)E2 * L_ * 2;          //  8,388,608
    const size_t perEb  = (size_t)L_ * L_ * 2;          // 33,554,432
    const size_t perOPT = (size_t)KSPLIT * E2 * L_ * 2; //  8,388,608
    const size_t per = perVT + perEb + perOPT;
    int nb = 1;
    if (ws_size >= base + 4 * per) nb = 4;
    else if (ws_size >= base + 2 * per) nb = 2;

    f16* VT  = (f16*)(w8 + base);
    f16* Eb  = (f16*)(w8 + base + (size_t)nb * perVT);
    f16* OPT = (f16*)(w8 + base + (size_t)nb * (perVT + perEb));

    resize_kernel<<<(B_ * C_ * HS * WS) / 256, 256, 0, stream>>>(fg, fgs);
    patch_kernel<<<dim3((L_ * K1) / 256, B_), 256, 0, stream>>>(fgs, P_all);
    norm_kernel<<<dim3(L_, B_), 64, 0, stream>>>(P_all, nrm);
    hipMemsetAsync(rowsum_all, 0, (size_t)B_ * L_ * sizeof(float), stream);

    for (int g = 0; g < B_; g += nb) {
        const f16* P_g     = P_all + (size_t)g * L_ * K1;
        const float* nrm_g = nrm + (size_t)g * L_;
        float* rowsum_g    = rowsum_all + (size_t)g * L_;
        int* flags_g       = flags + g * 1024;

        v_kernel<<<dim3((L_ * E2) / 256, nb), 256, 0, stream>>>(
            bg + (size_t)g * C_ * H_ * W_, VT);

        // E (both triangles from upper-triangle gram tiles) + rowsum + flags.
        // 1-D grid, XCD-pinned regions: 4 regions x 136 slots per sample.
        mfma_gemm<1><<<544 * nb, 256, 0, stream>>>(
            P_g, (size_t)L_ * K1, P_g, (size_t)L_ * K1,
            K1, K1, K1, Eb, (size_t)L_ * L_, L_,
            nrm_g, rowsum_g, flags_g);

        // OPT[e,p] = sum_l VT[e,l] * E[p,l]  (mask-driven tile skip),
        // 1-D grid, XCD-pinned VT e-panels per sample.
        mfma_gemm<0><<<256 * nb, 256, 0, stream>>>(
            VT, (size_t)E2 * L_, Eb, (size_t)L_ * L_,
            L_, L_, L_, OPT, (size_t)KSPLIT * E2 * L_, L_,
            nullptr, nullptr, flags_g);

        gather_kernel<<<dim3((C_ * H_ * W_) / 256, nb), 256, 0, stream>>>(
            OPT, rowsum_g, out + (size_t)g * C_ * H_ * W_);
    }
}

// Round 5
// 230.814 us; speedup vs baseline: 1.5854x; 1.0086x over previous
//
#include <hip/hip_runtime.h>
#include <hip/hip_bf16.h>
#include <math.h>

#define B_  4
#define C_  64
#define H_  128
#define W_  128
#define HS  64
#define WS  64
#define L_  4096
#define K1  576
#define E2  1024
#define KSPLIT 1
// f16 subnormal floor is 2^-24 (logit -16.635); values below 2^-25 (-17.33) cast
// to exactly 0. Flag threshold -17.5 is conservative: no nonzero f16 is missed.
#define ZLOG (-17.5f)

typedef _Float16 f16;
typedef f16 f16x8 __attribute__((ext_vector_type(8)));
typedef float f32x4 __attribute__((ext_vector_type(4)));

__device__ __forceinline__ void gload16(const void* g, void* l) {
    __builtin_amdgcn_global_load_lds(
        (const __attribute__((address_space(1))) unsigned int*)g,
        (__attribute__((address_space(3))) unsigned int*)l, 16, 0, 0);
}

// swizzled f16 index into a 128x128 LDS tile: 16B chunk XOR'd by row&7
// (write and readback use the same mapping -> bijective, conflict-reduced)
__device__ __forceinline__ int swz(int r, int c) {
    return r * 128 + ((((c >> 3) ^ (r & 7)) << 3) | (c & 7));
}

// ---------------- bilinear resize 128->64, align_corners ----------------
__global__ __launch_bounds__(256) void resize_kernel(const float* __restrict__ fg,
                                                     float* __restrict__ fgs) {
    int idx = blockIdx.x * 256 + threadIdx.x;
    if (idx >= B_ * C_ * HS * WS) return;
    int j = idx & 63, i = (idx >> 6) & 63, bc = idx >> 12;
    const float sc = 127.0f / 63.0f;
    float yf = i * sc, xf = j * sc;
    int y0 = (int)floorf(yf); if (y0 > 127) y0 = 127;
    int x0 = (int)floorf(xf); if (x0 > 127) x0 = 127;
    int y1 = min(y0 + 1, 127), x1 = min(x0 + 1, 127);
    float wy = yf - (float)y0, wx = xf - (float)x0;
    const float* p = fg + (size_t)bc * (H_ * W_);
    float a = p[y0 * W_ + x0], b = p[y0 * W_ + x1];
    float c = p[y1 * W_ + x0], d = p[y1 * W_ + x1];
    float t0 = a * (1.f - wy) + c * wy;
    float t1 = b * (1.f - wy) + d * wy;
    fgs[idx] = t0 * (1.f - wx) + t1 * wx;
}

// ---------------- P[l,k] f16 patches (3x3xC, zero pad 1), batched ----------------
__global__ __launch_bounds__(256) void patch_kernel(const float* __restrict__ fgs,
                                                    f16* __restrict__ P_all) {
    int idx = blockIdx.x * 256 + threadIdx.x;
    int b = blockIdx.y;
    int k = idx % K1, l = idx / K1;
    int c = k / 9, r = k % 9;
    int dy = r / 3, dx = r % 3;
    int ly = l >> 6, lx = l & 63;
    int y = ly - 1 + dy, x = lx - 1 + dx;
    float v = 0.f;
    if ((unsigned)y < 64u && (unsigned)x < 64u)
        v = fgs[((size_t)b * C_ + c) * (HS * WS) + y * WS + x];
    P_all[(size_t)b * L_ * K1 + idx] = (f16)v;
}

// ---------------- norms of f16 patch rows (fp32 accumulate), batched ----------------
__global__ __launch_bounds__(64) void norm_kernel(const f16* __restrict__ P_all,
                                                  float* __restrict__ nrm_all) {
    int l = blockIdx.x, b = blockIdx.y, t = threadIdx.x;
    const f16* row = P_all + ((size_t)b * L_ + l) * K1;
    float s = 0.f;
    for (int k = t; k < K1; k += 64) { float v = (float)row[k]; s = fmaf(v, v, s); }
    #pragma unroll
    for (int off = 32; off; off >>= 1) s += __shfl_down(s, off);
    if (t == 0) nrm_all[b * L_ + l] = fmaxf(sqrtf(s), 1e-4f);
}

// ---------------- VT[e,l] f16 : transposed 4x4xC background patches, batched over grid.y ----------------
__global__ __launch_bounds__(256) void v_kernel(const float* __restrict__ bg_g,
                                                f16* __restrict__ VT_g) {
    int ls = blockIdx.y;
    const float* bg_b = bg_g + (size_t)ls * (C_ * H_ * W_);
    f16* VT = VT_g + (size_t)ls * ((size_t)E2 * L_);
    int idx = blockIdx.x * 256 + threadIdx.x;
    int l = idx & 4095, e = idx >> 12;
    int c = e >> 4, r = e & 15;
    int ky = r >> 2, kx = r & 3;
    int ly = l >> 6, lx = l & 63;
    int by = 2 * ly - 1 + ky, bx = 2 * lx - 1 + kx;
    float v = 0.f;
    if ((unsigned)by < 128u && (unsigned)bx < 128u)
        v = bg_b[(size_t)c * (H_ * W_) + by * W_ + bx];
    VT[idx] = (f16)v;
}

// next flag-valid K position (64-elem chunk granularity, flags per 128)
__device__ __forceinline__ int nextk(int kn, int kLen, unsigned long long mask) {
    while (kn < kLen) {
        int t = kn >> 7;
        if (mask & (1ull << t)) return kn;
        unsigned long long m = mask >> t;
        if (!m) return kLen;
        kn = (t + __builtin_ctzll(m)) << 7;
    }
    return kn;
}

// ---------------- MFMA gemm_bt: D[M,N] = A[M,K] * Bt[N,K]^T ----------------
// 128x128 tile, 4 waves (2x2 of 64x64), 16x16x32 f16 MFMA, BK=64, T2 chunk
// XOR-swizzle (0 conflicts, r1), r4 XCD-pinned L2-locality schedule (FETCH
// verified 3x lower).
// r5: COUNTED-VMCNT 2-phase schedule (T3+T4). Per chunk:
//   s_barrier            (a: all waves done reading buf[nxt] last iteration)
//   issue 8 gload_lds -> buf[nxt]
//   s_waitcnt vmcnt(8)   (previous chunk's 8 loads complete; latency was
//                         hidden under the previous compute phase)
//   s_barrier            (b: cur buffer complete block-wide)
//   sched_barrier(0)     (rule #18: no ds_read hoisting above the wait)
//   ds_read + 64 MFMA (setprio 1)
// Never drains vmcnt to 0 in the main loop (T4) - the old __syncthreads
// forced vmcnt(0), exposing full load latency every chunk.
// EPI=1 epilogue (r3): both E triangles from one gram tile, max-logit pre-pass
//   skips exp/stores for all-zero tiles (f16-exact), coalesced LDS-staged
//   stores, rowsum atomics, per-tile flags.
// EPI=0 (PV): ballot flag mask, K-loop jumps to nonzero E-tiles only;
//   __syncthreads added before the As-reuse store tile (was covered by the
//   removed loop barrier).
template <int EPI>
__global__ __launch_bounds__(256)
void mfma_gemm(const f16* __restrict__ A, size_t sA,
               const f16* __restrict__ Bt, size_t sB,
               int lda, int ldb, int kLen, void* __restrict__ outp, size_t sOut,
               int ldc, const float* __restrict__ nrm, float* __restrict__ rowsum,
               int* __restrict__ flags) {
    // [buf][half][128 rows x 32 cols]; As doubles as the 128x128 f16 store tile
    __shared__ __align__(16) f16 As[2][2][128 * 32];
    __shared__ __align__(16) f16 Bs[2][2][128 * 32];
    __shared__ float sred[8];

    const int lin = blockIdx.x;
    const int S = gridDim.x >> 3;
    int bx, by, ls;
    if (EPI == 1) {
        int s = (lin & 7) * S + (lin >> 3);
        int R = s / 136, q = s - R * 136;
        ls = R >> 2;
        int rr = R & 3;
        if (rr < 2) {
            int a = 0;
            while (q >= 16 - a) { q -= 16 - a; ++a; }
            by = a + (rr << 4); bx = a + q + (rr << 4);
        } else {
            if (q >= 128) return;   // idle filler slot
            by = q & 15; bx = 16 + ((rr & 1) << 3) + (q >> 4);
        }
    } else {
        int G = (lin & 7) * S + (lin >> 3);
        ls = G >> 8;
        by = (G >> 5) & 7; bx = G & 31;   // by: e-tile, bx: p-tile
    }

    A  += (size_t)ls * sA;
    Bt += (size_t)ls * sB;
    f16* outbase = (f16*)outp + (size_t)ls * sOut;
    if (EPI == 1) { nrm += (size_t)ls * L_; rowsum += (size_t)ls * L_; }
    flags += ls * 1024;

    const int tid = threadIdx.x;
    const int w = tid >> 6, lane = tid & 63;
    const int row0 = by * 128, col0 = bx * 128;

    unsigned long long kmask = ~0ull;
    if (EPI == 0) {
        int f = (lane < 32) ? flags[bx * 32 + lane] : 0;
        kmask = __ballot(f != 0);
    }

    const int srow = w * 32 + (lane >> 2);
    // swizzled source chunk: LDS[row][q] holds global chunk q ^ ((row>>1)&3)
    const int scol = (((lane & 3) ^ ((lane >> 3) & 3)) * 8);
    const f16* gA = A + (size_t)(row0 + srow) * lda + scol;
    const f16* gB = Bt + (size_t)(col0 + srow) * ldb + scol;
    const int l0 = (w * 32) * 32, l1 = (w * 32 + 16) * 32;

    const int wm = w >> 1, wn = w & 1;
    const int mfm = lane & 15, quad = lane >> 4;
    // swizzled read chunk (element offset): undoes the staging permutation
    const int rq = (quad ^ ((mfm >> 1) & 3)) * 8;
    f32x4 acc[4][4] = {};

    int kc = (EPI == 0) ? nextk(0, kLen, kmask) : 0;
    if (kc < kLen) {
        int cur = 0;
        // prologue: issue chunk-kc loads into buffer 0 (no wait here; the
        // first loop iteration's vmcnt(8)/vmcnt(0) covers completion)
        gload16(gA + kc,                         &As[0][0][l0]);
        gload16(gA + kc + (size_t)16 * lda,      &As[0][0][l1]);
        gload16(gA + kc + 32,                    &As[0][1][l0]);
        gload16(gA + kc + 32 + (size_t)16 * lda, &As[0][1][l1]);
        gload16(gB + kc,                         &Bs[0][0][l0]);
        gload16(gB + kc + (size_t)16 * ldb,      &Bs[0][0][l1]);
        gload16(gB + kc + 32,                    &Bs[0][1][l0]);
        gload16(gB + kc + 32 + (size_t)16 * ldb, &Bs[0][1][l1]);
        for (;;) {
            int kn = (EPI == 0) ? nextk(kc + 64, kLen, kmask) : kc + 64;
            // (a) ensure every wave finished ds_reading buf[nxt] (iter t-1)
            __builtin_amdgcn_s_barrier();
            if (kn < kLen) {
                const int nxt = cur ^ 1;
                gload16(gA + kn,                         &As[nxt][0][l0]);
                gload16(gA + kn + (size_t)16 * lda,      &As[nxt][0][l1]);
                gload16(gA + kn + 32,                    &As[nxt][1][l0]);
                gload16(gA + kn + 32 + (size_t)16 * lda, &As[nxt][1][l1]);
                gload16(gB + kn,                         &Bs[nxt][0][l0]);
                gload16(gB + kn + (size_t)16 * ldb,      &Bs[nxt][0][l1]);
                gload16(gB + kn + 32,                    &Bs[nxt][1][l0]);
                gload16(gB + kn + 32 + (size_t)16 * ldb, &Bs[nxt][1][l1]);
                // wait only the PREVIOUS chunk's 8 loads (8 newest = prefetch
                // stay in flight across the barrier - T4 counted vmcnt)
                asm volatile("s_waitcnt vmcnt(8)" ::: "memory");
            } else {
                asm volatile("s_waitcnt vmcnt(0)" ::: "memory");
            }
            // (b) cur buffer complete for ALL waves
            __builtin_amdgcn_s_barrier();
            __builtin_amdgcn_sched_barrier(0);
            #pragma unroll
            for (int h = 0; h < 2; ++h) {
                f16x8 af[4], bf[4];
                #pragma unroll
                for (int mi = 0; mi < 4; ++mi)
                    af[mi] = *(const f16x8*)&As[cur][h][(wm * 64 + mi * 16 + mfm) * 32 + rq];
                #pragma unroll
                for (int ni = 0; ni < 4; ++ni)
                    bf[ni] = *(const f16x8*)&Bs[cur][h][(wn * 64 + ni * 16 + mfm) * 32 + rq];
                __builtin_amdgcn_s_setprio(1);
                #pragma unroll
                for (int mi = 0; mi < 4; ++mi)
                    #pragma unroll
                    for (int ni = 0; ni < 4; ++ni)
                        acc[mi][ni] = __builtin_amdgcn_mfma_f32_16x16x32_f16(
                            af[mi], bf[ni], acc[mi][ni], 0, 0, 0);
                __builtin_amdgcn_s_setprio(0);
            }
            cur ^= 1;
            kc = kn;
            if (kc >= kLen) break;
        }
    }

    const int orow = row0 + wm * 64;   // global row of this wave's quadrant
    const int ocol = col0 + wn * 64;   // global col
    f16* st = &As[0][0][0];            // 128x128 f16 tile (32 KB)

    if (EPI == 1) {
        f16* Eo = outbase;
        const bool offd = (by != bx);
        float rowm[16], cs[4], csr[16], cm2[4];
        #pragma unroll
        for (int j = 0; j < 16; ++j) {
            float n = nrm[orow + (j >> 2) * 16 + quad * 4 + (j & 3)];
            rowm[j] = 10.0f * n; csr[j] = 10.0f / n;
        }
        #pragma unroll
        for (int ni = 0; ni < 4; ++ni) {
            float n = nrm[ocol + ni * 16 + mfm];
            cs[ni] = 10.0f / n; cm2[ni] = 10.0f * n;
        }
        // max-logit pass (no exp): tile1 = E[p,l], tile2 = E[l,p] (off-diag)
        float mx1 = -1e30f, mx2 = -1e30f;
        #pragma unroll
        for (int ni = 0; ni < 4; ++ni)
            #pragma unroll
            for (int mi = 0; mi < 4; ++mi)
                #pragma unroll
                for (int r = 0; r < 4; ++r) {
                    float a = acc[mi][ni][r];
                    mx1 = fmaxf(mx1, a * cs[ni] - rowm[mi * 4 + r]);
                    mx2 = fmaxf(mx2, a * csr[mi * 4 + r] - cm2[ni]);
                }
        #pragma unroll
        for (int off = 32; off; off >>= 1) {
            mx1 = fmaxf(mx1, __shfl_xor(mx1, off));
            mx2 = fmaxf(mx2, __shfl_xor(mx2, off));
        }
        if (lane == 0) { sred[w] = mx1; sred[4 + w] = mx2; }
        __syncthreads();   // also separates last chunk's ds_reads from st reuse
        float b1 = fmaxf(fmaxf(sred[0], sred[1]), fmaxf(sred[2], sred[3]));
        float b2 = fmaxf(fmaxf(sred[4], sred[5]), fmaxf(sred[6], sred[7]));
        int nz1 = b1 > ZLOG;
        int nz2 = offd && (b2 > ZLOG);
        if (nz1) {
            float rs[16] = {};
            #pragma unroll
            for (int ni = 0; ni < 4; ++ni)
                #pragma unroll
                for (int mi = 0; mi < 4; ++mi)
                    #pragma unroll
                    for (int r = 0; r < 4; ++r) {
                        float e = __expf(acc[mi][ni][r] * cs[ni] - rowm[mi * 4 + r]);
                        rs[mi * 4 + r] += e;
                        st[swz(wm * 64 + mi * 16 + quad * 4 + r,
                               wn * 64 + ni * 16 + mfm)] = (f16)e;
                    }
            __syncthreads();
            #pragma unroll
            for (int it = 0; it < 8; ++it) {
                int chunk = it * 256 + tid;
                int row = chunk >> 4, c16 = chunk & 15;
                f16x8 v = *(const f16x8*)&st[row * 128 + ((c16 ^ (row & 7)) << 3)];
                *(f16x8*)&Eo[(size_t)(row0 + row) * ldc + col0 + c16 * 8] = v;
            }
            #pragma unroll
            for (int j = 0; j < 16; ++j) {
                float v = rs[j];
                v += __shfl_xor(v, 1); v += __shfl_xor(v, 2);
                v += __shfl_xor(v, 4); v += __shfl_xor(v, 8);
                if (mfm == 0)
                    atomicAdd(&rowsum[orow + (j >> 2) * 16 + quad * 4 + (j & 3)], v);
            }
        }
        if (nz2) {
            __syncthreads();   // protect st from tile1 readback
            float rs2[4] = {};
            #pragma unroll
            for (int ni = 0; ni < 4; ++ni)
                #pragma unroll
                for (int mi = 0; mi < 4; ++mi)
                    #pragma unroll
                    for (int r = 0; r < 4; ++r) {
                        float e = __expf(acc[mi][ni][r] * csr[mi * 4 + r] - cm2[ni]);
                        rs2[ni] += e;
                        st[swz(wn * 64 + ni * 16 + mfm,
                               wm * 64 + mi * 16 + quad * 4 + r)] = (f16)e;
                    }
            __syncthreads();
            #pragma unroll
            for (int it = 0; it < 8; ++it) {
                int chunk = it * 256 + tid;
                int row = chunk >> 4, c16 = chunk & 15;
                f16x8 v = *(const f16x8*)&st[row * 128 + ((c16 ^ (row & 7)) << 3)];
                *(f16x8*)&Eo[(size_t)(col0 + row) * ldc + row0 + c16 * 8] = v;
            }
            #pragma unroll
            for (int ni = 0; ni < 4; ++ni) {
                float v = rs2[ni];
                v += __shfl_xor(v, 16); v += __shfl_xor(v, 32);
                if (quad == 0)
                    atomicAdd(&rowsum[ocol + ni * 16 + mfm], v);
            }
        }
        if (tid == 0) {
            flags[by * 32 + bx] = nz1;
            if (offd) flags[bx * 32 + by] = nz2;
        }
    } else {
        __syncthreads();   // last chunk's ds_reads must finish before st reuse
        // coalesced store of the (often zero) 128x128 output tile
        #pragma unroll
        for (int ni = 0; ni < 4; ++ni)
            #pragma unroll
            for (int mi = 0; mi < 4; ++mi)
                #pragma unroll
                for (int r = 0; r < 4; ++r)
                    st[swz(wm * 64 + mi * 16 + quad * 4 + r,
                           wn * 64 + ni * 16 + mfm)] = (f16)acc[mi][ni][r];
        __syncthreads();
        f16* base = outbase + (size_t)row0 * ldc + col0;
        #pragma unroll
        for (int it = 0; it < 8; ++it) {
            int chunk = it * 256 + tid;
            int row = chunk >> 4, c16 = chunk & 15;
            f16x8 v = *(const f16x8*)&st[row * 128 + ((c16 ^ (row & 7)) << 3)];
            *(f16x8*)&base[(size_t)row * ldc + c16 * 8] = v;
        }
    }
}

// ---------------- conv_transpose overlap-add gather on OPT[e][p] layout, batched ----------------
__global__ __launch_bounds__(256) void gather_kernel(const f16* __restrict__ OPT_g,
                                                     const float* __restrict__ rowsum_g,
                                                     float* __restrict__ out_g) {
    int ls = blockIdx.y;
    const f16* OPT = OPT_g + (size_t)ls * ((size_t)KSPLIT * E2 * L_);
    const float* rowsum = rowsum_g + (size_t)ls * L_;
    float* out_b = out_g + (size_t)ls * (C_ * H_ * W_);
    int idx = blockIdx.x * 256 + threadIdx.x;
    if (idx >= C_ * H_ * W_) return;
    int X = idx & 127, Y = (idx >> 7) & 127, c = idx >> 14;
    int kyp = (Y + 1) & 1;
    int kxp = (X + 1) & 1;
    float sum = 0.f;
    #pragma unroll
    for (int ky = kyp; ky < 4; ky += 2) {
        int py = (Y + 1 - ky) >> 1;
        if ((unsigned)py >= 64u) continue;
        #pragma unroll
        for (int kx = kxp; kx < 4; kx += 2) {
            int px = (X + 1 - kx) >> 1;
            if ((unsigned)px >= 64u) continue;
            int p = py * 64 + px;
            int e = c * 16 + ky * 4 + kx;
            float v = 0.f;
            #pragma unroll
            for (int s = 0; s < KSPLIT; ++s)
                v += (float)OPT[((size_t)s * E2 + e) * L_ + p];
            sum += v * __builtin_amdgcn_rcpf(rowsum[p]);
        }
    }
    out_b[idx] = 0.25f * sum;
}

extern "C" void kernel_launch(void* const* d_in, const int* in_sizes, int n_in,
                              void* d_out, int out_size, void* d_ws, size_t ws_size,
                              hipStream_t stream) {
    const float* bg = (const float*)d_in[0];
    const float* fg = (const float*)d_in[1];
    float* out = (float*)d_out;
    char* w8 = (char*)d_ws;

    // fixed workspace region (bytes)
    float* fgs        = (float*)(w8);                 //  4,194,304
    f16*   P_all      = (f16*)  (w8 + 4194304);       // 18,874,368
    float* nrm        = (float*)(w8 + 23068672);      //     65,536
    float* rowsum_all = (float*)(w8 + 23134208);      //     65,536 (B_ x L_)
    int*   flags      = (int*)  (w8 + 23199744);      //     16,384 (B_ x 32x32 tile flags)
    const size_t base = 23216128;

    // per-sample buffers: VT 8 MiB + Eb 32 MiB + OPT 8 MiB = 48 MiB.
    // nb=4 -> 224.5 MB, nb=2 -> 123.9 MB (fits: proven >=174 MB), nb=1 -> 73.5 MB
    const size_t perVT  = (size_t)E2 * L_ * 2;          //  8,388,608
    const size_t perEb  = (size_t)L_ * L_ * 2;          // 33,554,432
    const size_t perOPT = (size_t)KSPLIT * E2 * L_ * 2; //  8,388,608
    const size_t per = perVT + perEb + perOPT;
    int nb = 1;
    if (ws_size >= base + 4 * per) nb = 4;
    else if (ws_size >= base + 2 * per) nb = 2;

    f16* VT  = (f16*)(w8 + base);
    f16* Eb  = (f16*)(w8 + base + (size_t)nb * perVT);
    f16* OPT = (f16*)(w8 + base + (size_t)nb * (perVT + perEb));

    resize_kernel<<<(B_ * C_ * HS * WS) / 256, 256, 0, stream>>>(fg, fgs);
    patch_kernel<<<dim3((L_ * K1) / 256, B_), 256, 0, stream>>>(fgs, P_all);
    norm_kernel<<<dim3(L_, B_), 64, 0, stream>>>(P_all, nrm);
    hipMemsetAsync(rowsum_all, 0, (size_t)B_ * L_ * sizeof(float), stream);

    for (int g = 0; g < B_; g += nb) {
        const f16* P_g     = P_all + (size_t)g * L_ * K1;
        const float* nrm_g = nrm + (size_t)g * L_;
        float* rowsum_g    = rowsum_all + (size_t)g * L_;
        int* flags_g       = flags + g * 1024;

        v_kernel<<<dim3((L_ * E2) / 256, nb), 256, 0, stream>>>(
            bg + (size_t)g * C_ * H_ * W_, VT);

        // E (both triangles from upper-triangle gram tiles) + rowsum + flags.
        // 1-D grid, XCD-pinned regions: 4 regions x 136 slots per sample.
        mfma_gemm<1><<<544 * nb, 256, 0, stream>>>(
            P_g, (size_t)L_ * K1, P_g, (size_t)L_ * K1,
            K1, K1, K1, Eb, (size_t)L_ * L_, L_,
            nrm_g, rowsum_g, flags_g);

        // OPT[e,p] = sum_l VT[e,l] * E[p,l]  (mask-driven tile skip),
        // 1-D grid, XCD-pinned VT e-panels per sample.
        mfma_gemm<0><<<256 * nb, 256, 0, stream>>>(
            VT, (size_t)E2 * L_, Eb, (size_t)L_ * L_,
            L_, L_, L_, OPT, (size_t)KSPLIT * E2 * L_, L_,
            nullptr, nullptr, flags_g);

        gather_kernel<<<dim3((C_ * H_ * W_) / 256, nb), 256, 0, stream>>>(
            OPT, rowsum_g, out + (size_t)g * C_ * H_ * W_);
    }
}